// Round 1
// baseline (981.009 us; speedup 1.0000x reference)
//
#include <hip/hip_runtime.h>
#include <math.h>

#ifndef M_PI
#define M_PI 3.14159265358979323846
#endif

// Problem constants (B=2, T=4096, Dm=1024, H=16, D=64, W_BLK=256, nb=16)
// Layouts:
//   query/key/value : (B,T,Dm) row-major  -> GEMM A of shape (8192,1024)
//   Wq/Wk/Wv/Wo     : (1024,1024) row-major; proj = X @ W^T  (contraction over fast dim of both)
//   q/k/v workspace : (B,H,T,D) row-major
//   attn out (ao)   : (B,T,Dm) row-major  -> final GEMM A
//   d_out           : (B,T,Dm) row-major fp32

// ---------------------------------------------------------------------------
// mask table: tab[h][idx], idx = rel + 255, rel in [-255, 0]
// ---------------------------------------------------------------------------
__global__ void mask_tab_kernel(const float* __restrict__ s_v, float* __restrict__ tab) {
    int h = blockIdx.x;
    int idx = threadIdx.x;                 // 0..255
    float w = expf(s_v[h]) + 1.0f;
    float rel = (float)(idx - 255);        // -255..0  (rel <= 0 always here)
    float val = 0.0f;
    if (rel > -w) {
        val = 0.5f * (cosf((float)M_PI * rel / w) + 1.0f);
    }
    tab[h * 256 + idx] = val;
}

// ---------------------------------------------------------------------------
// GEMM: C = A * B^T.  A: MxK row-major, Bm: NxK row-major.
// PERM=0: C row-major MxN.  PERM=1: C written in (B=2,H=16,T=4096,D=64) layout.
// 128x128 tile, BK=32, 256 threads, 8x8 micro-tile, fp32 VALU.
// ---------------------------------------------------------------------------
template <int PERM>
__global__ __launch_bounds__(256, 2) void gemm_abt(const float* __restrict__ A,
                                                   const float* __restrict__ Bm,
                                                   float* __restrict__ C,
                                                   int M, int N, int K) {
    __shared__ float As[32][128 + 4];
    __shared__ float Bs[32][128 + 4];

    const int tid = threadIdx.x;
    const int brow = blockIdx.y * 128;
    const int bcol = blockIdx.x * 128;

    const int lr = tid >> 1;               // 0..127 : row within tile
    const int lk = (tid & 1) * 16;         // 0 / 16 : k offset
    const float* aptr = A + (size_t)(brow + lr) * K + lk;
    const float* bptr = Bm + (size_t)(bcol + lr) * K + lk;

    const int ty = tid >> 4;               // 0..15
    const int tx = tid & 15;               // 0..15
    const int i0 = ty * 8;
    const int j0 = tx * 8;

    float acc[8][8];
#pragma unroll
    for (int a = 0; a < 8; a++)
#pragma unroll
        for (int b = 0; b < 8; b++) acc[a][b] = 0.0f;

    for (int kt = 0; kt < K; kt += 32) {
        float4 av[4], bv[4];
#pragma unroll
        for (int m = 0; m < 4; m++) {
            av[m] = *(const float4*)(aptr + kt + m * 4);
            bv[m] = *(const float4*)(bptr + kt + m * 4);
        }
        __syncthreads();                   // previous compute done
#pragma unroll
        for (int m = 0; m < 4; m++) {
            As[lk + m * 4 + 0][lr] = av[m].x;
            As[lk + m * 4 + 1][lr] = av[m].y;
            As[lk + m * 4 + 2][lr] = av[m].z;
            As[lk + m * 4 + 3][lr] = av[m].w;
            Bs[lk + m * 4 + 0][lr] = bv[m].x;
            Bs[lk + m * 4 + 1][lr] = bv[m].y;
            Bs[lk + m * 4 + 2][lr] = bv[m].z;
            Bs[lk + m * 4 + 3][lr] = bv[m].w;
        }
        __syncthreads();
#pragma unroll
        for (int kk = 0; kk < 32; kk++) {
            float4 a0 = *(const float4*)&As[kk][i0];
            float4 a1 = *(const float4*)&As[kk][i0 + 4];
            float4 b0 = *(const float4*)&Bs[kk][j0];
            float4 b1 = *(const float4*)&Bs[kk][j0 + 4];
            float ar[8] = {a0.x, a0.y, a0.z, a0.w, a1.x, a1.y, a1.z, a1.w};
            float br[8] = {b0.x, b0.y, b0.z, b0.w, b1.x, b1.y, b1.z, b1.w};
#pragma unroll
            for (int a = 0; a < 8; a++)
#pragma unroll
                for (int b = 0; b < 8; b++)
                    acc[a][b] = fmaf(ar[a], br[b], acc[a][b]);
        }
    }

    if (PERM == 0) {
#pragma unroll
        for (int a = 0; a < 8; a++) {
            int i = brow + i0 + a;
            float* dst = C + (size_t)i * N + bcol + j0;
            *(float4*)dst = make_float4(acc[a][0], acc[a][1], acc[a][2], acc[a][3]);
            *(float4*)(dst + 4) = make_float4(acc[a][4], acc[a][5], acc[a][6], acc[a][7]);
        }
    } else {
        const int j = bcol + j0;
        const int h = j >> 6;
        const int d = j & 63;              // j0 multiple of 8 -> all 8 cols in same head
#pragma unroll
        for (int a = 0; a < 8; a++) {
            int i = brow + i0 + a;
            int b = i >> 12;
            int t = i & 4095;
            float* dst = C + (((size_t)(b * 16 + h) * 4096 + t) * 64 + d);
            *(float4*)dst = make_float4(acc[a][0], acc[a][1], acc[a][2], acc[a][3]);
            *(float4*)(dst + 4) = make_float4(acc[a][4], acc[a][5], acc[a][6], acc[a][7]);
        }
    }
}

// ---------------------------------------------------------------------------
// per-head l2norm over D=64, in place on q/k/v workspace (each 131072 rows)
// ---------------------------------------------------------------------------
__global__ void l2norm_kernel(float* __restrict__ q, float* __restrict__ k,
                              float* __restrict__ v) {
    float* base = (blockIdx.z == 0) ? q : (blockIdx.z == 1) ? k : v;
    size_t row = (size_t)blockIdx.x * blockDim.x + threadIdx.x;
    float* p = base + row * 64;
    float4 buf[16];
    float s = 0.0f;
#pragma unroll
    for (int m = 0; m < 16; m++) {
        buf[m] = *(const float4*)(p + m * 4);
        s = fmaf(buf[m].x, buf[m].x, s);
        s = fmaf(buf[m].y, buf[m].y, s);
        s = fmaf(buf[m].z, buf[m].z, s);
        s = fmaf(buf[m].w, buf[m].w, s);
    }
    float n = sqrtf(s);
    float inv = 1.0f / fmaxf(n, 1e-8f);
#pragma unroll
    for (int m = 0; m < 16; m++) {
        buf[m].x *= inv; buf[m].y *= inv; buf[m].z *= inv; buf[m].w *= inv;
        *(float4*)(p + m * 4) = buf[m];
    }
}

// ---------------------------------------------------------------------------
// banded block attention.
// block = (b, h, n, sub): 128 q-rows (t = n*256 + sub*128 + [0,128))
// kc column j in [0,512): t_k = (n-1)*256 + j.  valid iff mask(rel)>0 and (n>0 or j>=256).
// ---------------------------------------------------------------------------
__global__ __launch_bounds__(256, 2) void attn_kernel(
        const float* __restrict__ q, const float* __restrict__ k,
        const float* __restrict__ v, const float* __restrict__ s_v,
        const float* __restrict__ s_r, const float* __restrict__ mask_tab,
        float* __restrict__ out) {
    __shared__ float qT[64][128 + 4];   // [d][i]
    __shared__ float kT[64][32 + 4];    // [d][j]
    __shared__ float vs[32][64 + 4];    // [j][d]
    __shared__ float aT[32][128 + 4];   // [j][i]
    __shared__ float msk[256];

    const int bx = blockIdx.x;
    const int sub = bx & 1;
    const int n = (bx >> 1) & 15;
    const int h = (bx >> 5) & 15;
    const int b = bx >> 9;
    const int bh = b * 16 + h;
    const int tid = threadIdx.x;

    msk[tid] = mask_tab[h * 256 + tid];
    const float w = expf(s_v[h]) + 1.0f;
    const float r = expf(s_r[h]) + 1.0f;

    const int row0 = n * 256 + sub * 128;
    const float* qbase = q + (size_t)bh * 4096 * 64;
    const float* kbase = k + (size_t)bh * 4096 * 64;
    const float* vbase = v + (size_t)bh * 4096 * 64;

    // stage qT (128 rows x 64 d, transposed)
    {
        const int rrow = tid >> 1;
        const int d0 = (tid & 1) * 32;
        const float* src = qbase + (size_t)(row0 + rrow) * 64 + d0;
#pragma unroll
        for (int m = 0; m < 32; m += 4) {
            float4 x = *(const float4*)(src + m);
            qT[d0 + m + 0][rrow] = x.x;
            qT[d0 + m + 1][rrow] = x.y;
            qT[d0 + m + 2][rrow] = x.z;
            qT[d0 + m + 3][rrow] = x.w;
        }
    }

    // band of live j columns for this sub-block: j > 256 + ii - w, j <= 256 + ii
    int jlo = (int)floorf(256.0f + (float)(sub * 128) - w) + 1;
    if (jlo < 0) jlo = 0;
    if (n == 0 && jlo < 256) jlo = 256;
    jlo &= ~31;                                 // align down; extra cols are masked 0
    const int jhi = 256 + sub * 128 + 127;      // inclusive, <= 511

    const int tiS = tid >> 3;   // 0..31
    const int tjS = tid & 7;    // 0..7
    const int i0s = tiS * 4;    // sim rows
    const int j0s = tjS * 4;    // sim cols
    const int i0p = tiS * 4;    // PV rows
    const int d0p = tjS * 8;    // PV d-cols

    float acc[4][8];
#pragma unroll
    for (int a = 0; a < 4; a++)
#pragma unroll
        for (int m = 0; m < 8; m++) acc[a][m] = 0.0f;

    __syncthreads();

    const int rr = tid >> 3;          // 0..31 : kc row within tile
    const int dd = (tid & 7) * 8;     // 0..56

    for (int jt = jlo; jt <= jhi; jt += 32) {
        const int tk = (n - 1) * 256 + jt + rr;        // always in [0,4096) given band clamps
        const float* ksrc = kbase + (size_t)tk * 64 + dd;
        const float* vsrc = vbase + (size_t)tk * 64 + dd;
        float4 k0 = *(const float4*)(ksrc);
        float4 k1 = *(const float4*)(ksrc + 4);
        float4 v0 = *(const float4*)(vsrc);
        float4 v1 = *(const float4*)(vsrc + 4);
        __syncthreads();                                // prev PV done reading vs/aT
        kT[dd + 0][rr] = k0.x; kT[dd + 1][rr] = k0.y;
        kT[dd + 2][rr] = k0.z; kT[dd + 3][rr] = k0.w;
        kT[dd + 4][rr] = k1.x; kT[dd + 5][rr] = k1.y;
        kT[dd + 6][rr] = k1.z; kT[dd + 7][rr] = k1.w;
        *(float4*)&vs[rr][dd] = v0;
        *(float4*)&vs[rr][dd + 4] = v1;
        __syncthreads();

        // sim 4x4 micro-tile, contraction over d=64
        float s4[4][4];
#pragma unroll
        for (int a = 0; a < 4; a++)
#pragma unroll
            for (int c = 0; c < 4; c++) s4[a][c] = 0.0f;
#pragma unroll 8
        for (int d = 0; d < 64; d++) {
            float4 qv = *(const float4*)&qT[d][i0s];
            float4 kv = *(const float4*)&kT[d][j0s];
            float qa[4] = {qv.x, qv.y, qv.z, qv.w};
            float kb[4] = {kv.x, kv.y, kv.z, kv.w};
#pragma unroll
            for (int a = 0; a < 4; a++)
#pragma unroll
                for (int c = 0; c < 4; c++)
                    s4[a][c] = fmaf(qa[a], kb[c], s4[a][c]);
        }
        // alpha = relu(1 - r(1-sim))^2 * mask, write transposed for PV
#pragma unroll
        for (int a = 0; a < 4; a++) {
            const int ii = sub * 128 + i0s + a;
#pragma unroll
            for (int c = 0; c < 4; c++) {
                const int j = jt + j0s + c;
                const int rel = j - 256 - ii;
                float m = (rel >= -255 && rel <= 0) ? msk[rel + 255] : 0.0f;
                float t1 = 1.0f - r * (1.0f - s4[a][c]);
                t1 = fmaxf(t1, 0.0f);
                aT[j0s + c][i0s + a] = t1 * t1 * m;
            }
        }
        __syncthreads();

        // PV: acc[i][d] += alpha[i][j] * v[j][d]
#pragma unroll 8
        for (int j = 0; j < 32; j++) {
            float4 avv = *(const float4*)&aT[j][i0p];
            float4 w0 = *(const float4*)&vs[j][d0p];
            float4 w1 = *(const float4*)&vs[j][d0p + 4];
            float aa[4] = {avv.x, avv.y, avv.z, avv.w};
            float vv[8] = {w0.x, w0.y, w0.z, w0.w, w1.x, w1.y, w1.z, w1.w};
#pragma unroll
            for (int a = 0; a < 4; a++)
#pragma unroll
                for (int m = 0; m < 8; m++)
                    acc[a][m] = fmaf(aa[a], vv[m], acc[a][m]);
        }
        // next iteration's first __syncthreads covers the RAW on vs/aT
    }

    // row norm + tanh scaling + write to (B,T,Dm)
#pragma unroll
    for (int a = 0; a < 4; a++) {
        float p = 0.0f;
#pragma unroll
        for (int m = 0; m < 8; m++) p = fmaf(acc[a][m], acc[a][m], p);
        p += __shfl_xor(p, 1);
        p += __shfl_xor(p, 2);
        p += __shfl_xor(p, 4);
        float nn = sqrtf(p);
        float sc = tanhf(nn) / (nn + 1e-8f);
        const int trow = row0 + i0p + a;
        float* dst = out + ((size_t)(b * 4096 + trow)) * 1024 + h * 64 + d0p;
        *(float4*)dst = make_float4(acc[a][0] * sc, acc[a][1] * sc,
                                    acc[a][2] * sc, acc[a][3] * sc);
        *(float4*)(dst + 4) = make_float4(acc[a][4] * sc, acc[a][5] * sc,
                                          acc[a][6] * sc, acc[a][7] * sc);
    }
}

// ---------------------------------------------------------------------------
extern "C" void kernel_launch(void* const* d_in, const int* in_sizes, int n_in,
                              void* d_out, int out_size, void* d_ws, size_t ws_size,
                              hipStream_t stream) {
    const float* query = (const float*)d_in[0];
    const float* key   = (const float*)d_in[1];
    const float* value = (const float*)d_in[2];
    const float* Wq    = (const float*)d_in[3];
    const float* Wk    = (const float*)d_in[4];
    const float* Wv    = (const float*)d_in[5];
    const float* Wo    = (const float*)d_in[6];
    const float* s_v   = (const float*)d_in[7];
    const float* s_r   = (const float*)d_in[8];
    float* out = (float*)d_out;

    const size_t PROJ = (size_t)2 * 16 * 4096 * 64;   // 8,388,608 floats
    float* qw = (float*)d_ws;
    float* kw = qw + PROJ;
    float* vw = kw + PROJ;
    float* ao = vw + PROJ;
    float* mask = ao + PROJ;                          // 16*256 floats

    mask_tab_kernel<<<dim3(16), dim3(256), 0, stream>>>(s_v, mask);

    dim3 gb(1024 / 128, 8192 / 128);                  // (N/128, M/128)
    gemm_abt<1><<<gb, dim3(256), 0, stream>>>(query, Wq, qw, 8192, 1024, 1024);
    gemm_abt<1><<<gb, dim3(256), 0, stream>>>(key,   Wk, kw, 8192, 1024, 1024);
    gemm_abt<1><<<gb, dim3(256), 0, stream>>>(value, Wv, vw, 8192, 1024, 1024);

    l2norm_kernel<<<dim3(512, 1, 3), dim3(256), 0, stream>>>(qw, kw, vw);

    attn_kernel<<<dim3(1024), dim3(256), 0, stream>>>(qw, kw, vw, s_v, s_r, mask, ao);

    gemm_abt<0><<<gb, dim3(256), 0, stream>>>(ao, Wo, out, 8192, 1024, 1024);
}

// Round 2
// 571.659 us; speedup vs baseline: 1.7161x; 1.7161x over previous
//
#include <hip/hip_runtime.h>
#include <math.h>

#ifndef M_PI
#define M_PI 3.14159265358979323846
#endif

typedef short bf16x8 __attribute__((ext_vector_type(8)));
typedef float f32x4 __attribute__((ext_vector_type(4)));

#define LDS_STRIDE 40   // ushorts per row: 80 B -> 16B-aligned rows, bank-friendly

// ---------------------------------------------------------------------------
// mask table: tab[h][idx], idx = rel + 255, rel in [-255, 0]
// ---------------------------------------------------------------------------
__global__ void mask_tab_kernel(const float* __restrict__ s_v, float* __restrict__ tab) {
    int h = blockIdx.x;
    int idx = threadIdx.x;                 // 0..255
    float w = expf(s_v[h]) + 1.0f;
    float rel = (float)(idx - 255);        // -255..0
    float val = 0.0f;
    if (rel > -w) {
        val = 0.5f * (cosf((float)M_PI * rel / w) + 1.0f);
    }
    tab[h * 256 + idx] = val;
}

// ---------------------------------------------------------------------------
// split one f32x4 into hi/mid/lo bf16 (bit-truncation; subtractions exact)
// and store packed (4 bf16 = 8B) into the three LDS tiles.
// ---------------------------------------------------------------------------
__device__ __forceinline__ void split_write(unsigned short* ph, unsigned short* pm,
                                            unsigned short* pl, int off, f32x4 x) {
    unsigned int hb[4], mb[4], lb[4];
#pragma unroll
    for (int i = 0; i < 4; i++) {
        float xi = x[i];
        unsigned int u = __float_as_uint(xi);
        hb[i] = u & 0xFFFF0000u;
        float r1 = xi - __uint_as_float(hb[i]);
        mb[i] = __float_as_uint(r1) & 0xFFFF0000u;
        float r2 = r1 - __uint_as_float(mb[i]);
        lb[i] = __float_as_uint(r2);
    }
    uint2 hp, mp, lp;
    hp.x = (hb[0] >> 16) | hb[1];
    hp.y = (hb[2] >> 16) | hb[3];
    mp.x = (mb[0] >> 16) | mb[1];
    mp.y = (mb[2] >> 16) | mb[3];
    lp.x = (lb[0] >> 16) | (lb[1] & 0xFFFF0000u);
    lp.y = (lb[2] >> 16) | (lb[3] & 0xFFFF0000u);
    *(uint2*)(ph + off) = hp;
    *(uint2*)(pm + off) = mp;
    *(uint2*)(pl + off) = lp;
}

// ---------------------------------------------------------------------------
// GEMM: C = A * Bm^T via 6-product bf16 split MFMA.
// A: MxK f32 row-major, Bm: NxK f32 row-major.
// PERM=0: C row-major MxN f32.  PERM=1: C in (B=2,H=16,T=4096,D=64) layout.
// 128x128 tile, BK=32, 256 threads (4 waves, 2x2), 4x4 16x16x32 frags/wave.
// ---------------------------------------------------------------------------
template <int PERM>
__global__ __launch_bounds__(256, 2) void gemm_mfma6(const float* __restrict__ A,
                                                     const float* __restrict__ Bm,
                                                     float* __restrict__ C,
                                                     int M, int N, int K) {
    __shared__ unsigned short Ah[128 * LDS_STRIDE];
    __shared__ unsigned short Amd[128 * LDS_STRIDE];
    __shared__ unsigned short Al[128 * LDS_STRIDE];
    __shared__ unsigned short Bh[128 * LDS_STRIDE];
    __shared__ unsigned short Bmd[128 * LDS_STRIDE];
    __shared__ unsigned short Bl[128 * LDS_STRIDE];

    const int tid = threadIdx.x;
    const int brow = blockIdx.y * 128;
    const int bcol = blockIdx.x * 128;
    const int lane = tid & 63;
    const int wv = tid >> 6;
    const int wr = wv >> 1;
    const int wc = wv & 1;

    // staging assignment: thread -> (row, 16-wide k slice)
    const int srow = tid >> 1;            // 0..127
    const int skb = (tid & 1) * 16;       // 0 / 16
    const float* aptr = A + (size_t)(brow + srow) * K + skb;
    const float* bptr = Bm + (size_t)(bcol + srow) * K + skb;
    const int soff = srow * LDS_STRIDE + skb;

    const int l15 = lane & 15;
    const int k8 = (lane >> 4) * 8;

    f32x4 acc[4][4];
#pragma unroll
    for (int a = 0; a < 4; a++)
#pragma unroll
        for (int b = 0; b < 4; b++) acc[a][b] = (f32x4)(0.0f);

    f32x4 abuf[4], bbuf[4];
#pragma unroll
    for (int m = 0; m < 4; m++) {
        abuf[m] = *(const f32x4*)(aptr + m * 4);
        bbuf[m] = *(const f32x4*)(bptr + m * 4);
    }

#define MFMA_TILE(AF, BF)                                                            \
    do {                                                                             \
        _Pragma("unroll") for (int fr = 0; fr < 4; fr++)                             \
            _Pragma("unroll") for (int fc = 0; fc < 4; fc++)                         \
                acc[fr][fc] = __builtin_amdgcn_mfma_f32_16x16x32_bf16(               \
                    AF[fr], BF[fc], acc[fr][fc], 0, 0, 0);                           \
    } while (0)

    for (int kt = 0; kt < K; kt += 32) {
        __syncthreads();   // previous MFMA phase done reading LDS
#pragma unroll
        for (int m = 0; m < 4; m++) {
            split_write(Ah, Amd, Al, soff + m * 4, abuf[m]);
            split_write(Bh, Bmd, Bl, soff + m * 4, bbuf[m]);
        }
        if (kt + 32 < K) {   // prefetch next fp32 K-slice; latency hides under MFMA
#pragma unroll
            for (int m = 0; m < 4; m++) {
                abuf[m] = *(const f32x4*)(aptr + kt + 32 + m * 4);
                bbuf[m] = *(const f32x4*)(bptr + kt + 32 + m * 4);
            }
        }
        __syncthreads();   // LDS tiles visible

        bf16x8 ah[4], bh[4], t1[4], t2[4];
#pragma unroll
        for (int f = 0; f < 4; f++) {
            ah[f] = *(const bf16x8*)&Ah[(wr * 64 + f * 16 + l15) * LDS_STRIDE + k8];
            bh[f] = *(const bf16x8*)&Bh[(wc * 64 + f * 16 + l15) * LDS_STRIDE + k8];
        }
        MFMA_TILE(ah, bh);                      // hi * hi
#pragma unroll
        for (int f = 0; f < 4; f++)
            t1[f] = *(const bf16x8*)&Bmd[(wc * 64 + f * 16 + l15) * LDS_STRIDE + k8];
        MFMA_TILE(ah, t1);                      // hi * mid
#pragma unroll
        for (int f = 0; f < 4; f++)
            t2[f] = *(const bf16x8*)&Amd[(wr * 64 + f * 16 + l15) * LDS_STRIDE + k8];
        MFMA_TILE(t2, t1);                      // mid * mid
        MFMA_TILE(t2, bh);                      // mid * hi
#pragma unroll
        for (int f = 0; f < 4; f++)
            t1[f] = *(const bf16x8*)&Bl[(wc * 64 + f * 16 + l15) * LDS_STRIDE + k8];
        MFMA_TILE(ah, t1);                      // hi * lo
#pragma unroll
        for (int f = 0; f < 4; f++)
            t2[f] = *(const bf16x8*)&Al[(wr * 64 + f * 16 + l15) * LDS_STRIDE + k8];
        MFMA_TILE(t2, bh);                      // lo * hi
    }
#undef MFMA_TILE

    // epilogue: C/D layout col = lane&15, row = (lane>>4)*4 + reg
    const int rsub = (lane >> 4) * 4;
#pragma unroll
    for (int fr = 0; fr < 4; fr++) {
#pragma unroll
        for (int fc = 0; fc < 4; fc++) {
            f32x4 v = acc[fr][fc];
            const int i0 = brow + wr * 64 + fr * 16 + rsub;
            const int j = bcol + wc * 64 + fc * 16 + l15;
            if (PERM == 0) {
#pragma unroll
                for (int r = 0; r < 4; r++) C[(size_t)(i0 + r) * N + j] = v[r];
            } else {
                const int h = j >> 6;
                const int d = j & 63;
#pragma unroll
                for (int r = 0; r < 4; r++) {
                    const int i = i0 + r;
                    const int b = i >> 12;
                    const int t = i & 4095;
                    C[(((size_t)(b * 16 + h) * 4096 + t) * 64 + d)] = v[r];
                }
            }
        }
    }
}

// ---------------------------------------------------------------------------
// per-head l2norm over D=64, in place on q/k/v workspace (each 131072 rows)
// ---------------------------------------------------------------------------
__global__ void l2norm_kernel(float* __restrict__ q, float* __restrict__ k,
                              float* __restrict__ v) {
    float* base = (blockIdx.z == 0) ? q : (blockIdx.z == 1) ? k : v;
    size_t row = (size_t)blockIdx.x * blockDim.x + threadIdx.x;
    float* p = base + row * 64;
    float4 buf[16];
    float s = 0.0f;
#pragma unroll
    for (int m = 0; m < 16; m++) {
        buf[m] = *(const float4*)(p + m * 4);
        s = fmaf(buf[m].x, buf[m].x, s);
        s = fmaf(buf[m].y, buf[m].y, s);
        s = fmaf(buf[m].z, buf[m].z, s);
        s = fmaf(buf[m].w, buf[m].w, s);
    }
    float n = sqrtf(s);
    float inv = 1.0f / fmaxf(n, 1e-8f);
#pragma unroll
    for (int m = 0; m < 16; m++) {
        buf[m].x *= inv; buf[m].y *= inv; buf[m].z *= inv; buf[m].w *= inv;
        *(float4*)(p + m * 4) = buf[m];
    }
}

// ---------------------------------------------------------------------------
// banded block attention (fp32, unchanged from round 1).
// ---------------------------------------------------------------------------
__global__ __launch_bounds__(256, 2) void attn_kernel(
        const float* __restrict__ q, const float* __restrict__ k,
        const float* __restrict__ v, const float* __restrict__ s_v,
        const float* __restrict__ s_r, const float* __restrict__ mask_tab,
        float* __restrict__ out) {
    __shared__ float qT[64][128 + 4];   // [d][i]
    __shared__ float kT[64][32 + 4];    // [d][j]
    __shared__ float vs[32][64 + 4];    // [j][d]
    __shared__ float aT[32][128 + 4];   // [j][i]
    __shared__ float msk[256];

    const int bx = blockIdx.x;
    const int sub = bx & 1;
    const int n = (bx >> 1) & 15;
    const int h = (bx >> 5) & 15;
    const int b = bx >> 9;
    const int bh = b * 16 + h;
    const int tid = threadIdx.x;

    msk[tid] = mask_tab[h * 256 + tid];
    const float w = expf(s_v[h]) + 1.0f;
    const float r = expf(s_r[h]) + 1.0f;

    const int row0 = n * 256 + sub * 128;
    const float* qbase = q + (size_t)bh * 4096 * 64;
    const float* kbase = k + (size_t)bh * 4096 * 64;
    const float* vbase = v + (size_t)bh * 4096 * 64;

    {
        const int rrow = tid >> 1;
        const int d0 = (tid & 1) * 32;
        const float* src = qbase + (size_t)(row0 + rrow) * 64 + d0;
#pragma unroll
        for (int m = 0; m < 32; m += 4) {
            float4 x = *(const float4*)(src + m);
            qT[d0 + m + 0][rrow] = x.x;
            qT[d0 + m + 1][rrow] = x.y;
            qT[d0 + m + 2][rrow] = x.z;
            qT[d0 + m + 3][rrow] = x.w;
        }
    }

    int jlo = (int)floorf(256.0f + (float)(sub * 128) - w) + 1;
    if (jlo < 0) jlo = 0;
    if (n == 0 && jlo < 256) jlo = 256;
    jlo &= ~31;
    const int jhi = 256 + sub * 128 + 127;

    const int tiS = tid >> 3;
    const int tjS = tid & 7;
    const int i0s = tiS * 4;
    const int j0s = tjS * 4;
    const int i0p = tiS * 4;
    const int d0p = tjS * 8;

    float acc[4][8];
#pragma unroll
    for (int a = 0; a < 4; a++)
#pragma unroll
        for (int m = 0; m < 8; m++) acc[a][m] = 0.0f;

    __syncthreads();

    const int rr = tid >> 3;
    const int dd = (tid & 7) * 8;

    for (int jt = jlo; jt <= jhi; jt += 32) {
        const int tk = (n - 1) * 256 + jt + rr;
        const float* ksrc = kbase + (size_t)tk * 64 + dd;
        const float* vsrc = vbase + (size_t)tk * 64 + dd;
        float4 k0 = *(const float4*)(ksrc);
        float4 k1 = *(const float4*)(ksrc + 4);
        float4 v0 = *(const float4*)(vsrc);
        float4 v1 = *(const float4*)(vsrc + 4);
        __syncthreads();
        kT[dd + 0][rr] = k0.x; kT[dd + 1][rr] = k0.y;
        kT[dd + 2][rr] = k0.z; kT[dd + 3][rr] = k0.w;
        kT[dd + 4][rr] = k1.x; kT[dd + 5][rr] = k1.y;
        kT[dd + 6][rr] = k1.z; kT[dd + 7][rr] = k1.w;
        *(float4*)&vs[rr][dd] = v0;
        *(float4*)&vs[rr][dd + 4] = v1;
        __syncthreads();

        float s4[4][4];
#pragma unroll
        for (int a = 0; a < 4; a++)
#pragma unroll
            for (int c = 0; c < 4; c++) s4[a][c] = 0.0f;
#pragma unroll 8
        for (int d = 0; d < 64; d++) {
            float4 qv = *(const float4*)&qT[d][i0s];
            float4 kv = *(const float4*)&kT[d][j0s];
            float qa[4] = {qv.x, qv.y, qv.z, qv.w};
            float kb[4] = {kv.x, kv.y, kv.z, kv.w};
#pragma unroll
            for (int a = 0; a < 4; a++)
#pragma unroll
                for (int c = 0; c < 4; c++)
                    s4[a][c] = fmaf(qa[a], kb[c], s4[a][c]);
        }
#pragma unroll
        for (int a = 0; a < 4; a++) {
            const int ii = sub * 128 + i0s + a;
#pragma unroll
            for (int c = 0; c < 4; c++) {
                const int j = jt + j0s + c;
                const int rel = j - 256 - ii;
                float m = (rel >= -255 && rel <= 0) ? msk[rel + 255] : 0.0f;
                float t1 = 1.0f - r * (1.0f - s4[a][c]);
                t1 = fmaxf(t1, 0.0f);
                aT[j0s + c][i0s + a] = t1 * t1 * m;
            }
        }
        __syncthreads();

#pragma unroll 8
        for (int j = 0; j < 32; j++) {
            float4 avv = *(const float4*)&aT[j][i0p];
            float4 w0 = *(const float4*)&vs[j][d0p];
            float4 w1 = *(const float4*)&vs[j][d0p + 4];
            float aa[4] = {avv.x, avv.y, avv.z, avv.w};
            float vv[8] = {w0.x, w0.y, w0.z, w0.w, w1.x, w1.y, w1.z, w1.w};
#pragma unroll
            for (int a = 0; a < 4; a++)
#pragma unroll
                for (int m = 0; m < 8; m++)
                    acc[a][m] = fmaf(aa[a], vv[m], acc[a][m]);
        }
    }

#pragma unroll
    for (int a = 0; a < 4; a++) {
        float p = 0.0f;
#pragma unroll
        for (int m = 0; m < 8; m++) p = fmaf(acc[a][m], acc[a][m], p);
        p += __shfl_xor(p, 1);
        p += __shfl_xor(p, 2);
        p += __shfl_xor(p, 4);
        float nn = sqrtf(p);
        float sc = tanhf(nn) / (nn + 1e-8f);
        const int trow = row0 + i0p + a;
        float* dst = out + ((size_t)(b * 4096 + trow)) * 1024 + h * 64 + d0p;
        *(float4*)dst = make_float4(acc[a][0] * sc, acc[a][1] * sc,
                                    acc[a][2] * sc, acc[a][3] * sc);
        *(float4*)(dst + 4) = make_float4(acc[a][4] * sc, acc[a][5] * sc,
                                          acc[a][6] * sc, acc[a][7] * sc);
    }
}

// ---------------------------------------------------------------------------
extern "C" void kernel_launch(void* const* d_in, const int* in_sizes, int n_in,
                              void* d_out, int out_size, void* d_ws, size_t ws_size,
                              hipStream_t stream) {
    const float* query = (const float*)d_in[0];
    const float* key   = (const float*)d_in[1];
    const float* value = (const float*)d_in[2];
    const float* Wq    = (const float*)d_in[3];
    const float* Wk    = (const float*)d_in[4];
    const float* Wv    = (const float*)d_in[5];
    const float* Wo    = (const float*)d_in[6];
    const float* s_v   = (const float*)d_in[7];
    const float* s_r   = (const float*)d_in[8];
    float* out = (float*)d_out;

    const size_t PROJ = (size_t)2 * 16 * 4096 * 64;   // 8,388,608 floats
    float* qw = (float*)d_ws;
    float* kw = qw + PROJ;
    float* vw = kw + PROJ;
    float* ao = vw + PROJ;
    float* mask = ao + PROJ;                          // 16*256 floats

    mask_tab_kernel<<<dim3(16), dim3(256), 0, stream>>>(s_v, mask);

    dim3 gb(1024 / 128, 8192 / 128);                  // (N/128, M/128)
    gemm_mfma6<1><<<gb, dim3(256), 0, stream>>>(query, Wq, qw, 8192, 1024, 1024);
    gemm_mfma6<1><<<gb, dim3(256), 0, stream>>>(key,   Wk, kw, 8192, 1024, 1024);
    gemm_mfma6<1><<<gb, dim3(256), 0, stream>>>(value, Wv, vw, 8192, 1024, 1024);

    l2norm_kernel<<<dim3(512, 1, 3), dim3(256), 0, stream>>>(qw, kw, vw);

    attn_kernel<<<dim3(1024), dim3(256), 0, stream>>>(qw, kw, vw, s_v, s_r, mask, ao);

    gemm_mfma6<0><<<gb, dim3(256), 0, stream>>>(ao, Wo, out, 8192, 1024, 1024);
}

// Round 3
// 506.856 us; speedup vs baseline: 1.9355x; 1.1279x over previous
//
#include <hip/hip_runtime.h>
#include <math.h>

#ifndef M_PI
#define M_PI 3.14159265358979323846
#endif

typedef short bf16x8 __attribute__((ext_vector_type(8)));
typedef float f32x4 __attribute__((ext_vector_type(4)));

#define LDS_STRIDE 40   // GEMM: ushorts per row

union FragU { uint4 u; bf16x8 f; };

// round-to-nearest-even bf16, returned as bits in HIGH 16 (low 16 zero)
__device__ __forceinline__ unsigned rn_hi(float x) {
    unsigned u = __float_as_uint(x);
    unsigned r = u + 0x7FFFu + ((u >> 16) & 1u);
    return r & 0xFFFF0000u;
}

// ---------------------------------------------------------------------------
// mask table: tab[h][idx], idx = rel + 255, rel in [-255, 0]
// ---------------------------------------------------------------------------
__global__ void mask_tab_kernel(const float* __restrict__ s_v, float* __restrict__ tab) {
    int h = blockIdx.x;
    int idx = threadIdx.x;
    float w = expf(s_v[h]) + 1.0f;
    float rel = (float)(idx - 255);
    float val = 0.0f;
    if (rel > -w) {
        val = 0.5f * (cosf((float)M_PI * rel / w) + 1.0f);
    }
    tab[h * 256 + idx] = val;
}

// ---------------------------------------------------------------------------
// GEMM (unchanged from round 2): C = A * Bm^T via 6-product bf16 split MFMA.
// ---------------------------------------------------------------------------
__device__ __forceinline__ void split_write(unsigned short* ph, unsigned short* pm,
                                            unsigned short* pl, int off, f32x4 x) {
    unsigned int hb[4], mb[4], lb[4];
#pragma unroll
    for (int i = 0; i < 4; i++) {
        float xi = x[i];
        unsigned int u = __float_as_uint(xi);
        hb[i] = u & 0xFFFF0000u;
        float r1 = xi - __uint_as_float(hb[i]);
        mb[i] = __float_as_uint(r1) & 0xFFFF0000u;
        float r2 = r1 - __uint_as_float(mb[i]);
        lb[i] = __float_as_uint(r2);
    }
    uint2 hp, mp, lp;
    hp.x = (hb[0] >> 16) | hb[1];
    hp.y = (hb[2] >> 16) | hb[3];
    mp.x = (mb[0] >> 16) | mb[1];
    mp.y = (mb[2] >> 16) | mb[3];
    lp.x = (lb[0] >> 16) | (lb[1] & 0xFFFF0000u);
    lp.y = (lb[2] >> 16) | (lb[3] & 0xFFFF0000u);
    *(uint2*)(ph + off) = hp;
    *(uint2*)(pm + off) = mp;
    *(uint2*)(pl + off) = lp;
}

template <int PERM>
__global__ __launch_bounds__(256, 2) void gemm_mfma6(const float* __restrict__ A,
                                                     const float* __restrict__ Bm,
                                                     float* __restrict__ C,
                                                     int M, int N, int K) {
    __shared__ unsigned short Ah[128 * LDS_STRIDE];
    __shared__ unsigned short Amd[128 * LDS_STRIDE];
    __shared__ unsigned short Al[128 * LDS_STRIDE];
    __shared__ unsigned short Bh[128 * LDS_STRIDE];
    __shared__ unsigned short Bmd[128 * LDS_STRIDE];
    __shared__ unsigned short Bl[128 * LDS_STRIDE];

    const int tid = threadIdx.x;
    const int brow = blockIdx.y * 128;
    const int bcol = blockIdx.x * 128;
    const int lane = tid & 63;
    const int wv = tid >> 6;
    const int wr = wv >> 1;
    const int wc = wv & 1;

    const int srow = tid >> 1;
    const int skb = (tid & 1) * 16;
    const float* aptr = A + (size_t)(brow + srow) * K + skb;
    const float* bptr = Bm + (size_t)(bcol + srow) * K + skb;
    const int soff = srow * LDS_STRIDE + skb;

    const int l15 = lane & 15;
    const int k8 = (lane >> 4) * 8;

    f32x4 acc[4][4];
#pragma unroll
    for (int a = 0; a < 4; a++)
#pragma unroll
        for (int b = 0; b < 4; b++) acc[a][b] = (f32x4)(0.0f);

    f32x4 abuf[4], bbuf[4];
#pragma unroll
    for (int m = 0; m < 4; m++) {
        abuf[m] = *(const f32x4*)(aptr + m * 4);
        bbuf[m] = *(const f32x4*)(bptr + m * 4);
    }

#define MFMA_TILE(AF, BF)                                                            \
    do {                                                                             \
        _Pragma("unroll") for (int fr = 0; fr < 4; fr++)                             \
            _Pragma("unroll") for (int fc = 0; fc < 4; fc++)                         \
                acc[fr][fc] = __builtin_amdgcn_mfma_f32_16x16x32_bf16(               \
                    AF[fr], BF[fc], acc[fr][fc], 0, 0, 0);                           \
    } while (0)

    for (int kt = 0; kt < K; kt += 32) {
        __syncthreads();
#pragma unroll
        for (int m = 0; m < 4; m++) {
            split_write(Ah, Amd, Al, soff + m * 4, abuf[m]);
            split_write(Bh, Bmd, Bl, soff + m * 4, bbuf[m]);
        }
        if (kt + 32 < K) {
#pragma unroll
            for (int m = 0; m < 4; m++) {
                abuf[m] = *(const f32x4*)(aptr + kt + 32 + m * 4);
                bbuf[m] = *(const f32x4*)(bptr + kt + 32 + m * 4);
            }
        }
        __syncthreads();

        bf16x8 ah[4], bh[4], t1[4], t2[4];
#pragma unroll
        for (int f = 0; f < 4; f++) {
            ah[f] = *(const bf16x8*)&Ah[(wr * 64 + f * 16 + l15) * LDS_STRIDE + k8];
            bh[f] = *(const bf16x8*)&Bh[(wc * 64 + f * 16 + l15) * LDS_STRIDE + k8];
        }
        MFMA_TILE(ah, bh);
#pragma unroll
        for (int f = 0; f < 4; f++)
            t1[f] = *(const bf16x8*)&Bmd[(wc * 64 + f * 16 + l15) * LDS_STRIDE + k8];
        MFMA_TILE(ah, t1);
#pragma unroll
        for (int f = 0; f < 4; f++)
            t2[f] = *(const bf16x8*)&Amd[(wr * 64 + f * 16 + l15) * LDS_STRIDE + k8];
        MFMA_TILE(t2, t1);
        MFMA_TILE(t2, bh);
#pragma unroll
        for (int f = 0; f < 4; f++)
            t1[f] = *(const bf16x8*)&Bl[(wc * 64 + f * 16 + l15) * LDS_STRIDE + k8];
        MFMA_TILE(ah, t1);
#pragma unroll
        for (int f = 0; f < 4; f++)
            t2[f] = *(const bf16x8*)&Al[(wr * 64 + f * 16 + l15) * LDS_STRIDE + k8];
        MFMA_TILE(t2, bh);
    }
#undef MFMA_TILE

    const int rsub = (lane >> 4) * 4;
#pragma unroll
    for (int fr = 0; fr < 4; fr++) {
#pragma unroll
        for (int fc = 0; fc < 4; fc++) {
            f32x4 v = acc[fr][fc];
            const int i0 = brow + wr * 64 + fr * 16 + rsub;
            const int j = bcol + wc * 64 + fc * 16 + l15;
            if (PERM == 0) {
#pragma unroll
                for (int r = 0; r < 4; r++) C[(size_t)(i0 + r) * N + j] = v[r];
            } else {
                const int h = j >> 6;
                const int d = j & 63;
#pragma unroll
                for (int r = 0; r < 4; r++) {
                    const int i = i0 + r;
                    const int b = i >> 12;
                    const int t = i & 4095;
                    C[(((size_t)(b * 16 + h) * 4096 + t) * 64 + d)] = v[r];
                }
            }
        }
    }
}

// ---------------------------------------------------------------------------
// per-head l2norm over D=64, in place
// ---------------------------------------------------------------------------
__global__ void l2norm_kernel(float* __restrict__ q, float* __restrict__ k,
                              float* __restrict__ v) {
    float* base = (blockIdx.z == 0) ? q : (blockIdx.z == 1) ? k : v;
    size_t row = (size_t)blockIdx.x * blockDim.x + threadIdx.x;
    float* p = base + row * 64;
    float4 buf[16];
    float s = 0.0f;
#pragma unroll
    for (int m = 0; m < 16; m++) {
        buf[m] = *(const float4*)(p + m * 4);
        s = fmaf(buf[m].x, buf[m].x, s);
        s = fmaf(buf[m].y, buf[m].y, s);
        s = fmaf(buf[m].z, buf[m].z, s);
        s = fmaf(buf[m].w, buf[m].w, s);
    }
    float n = sqrtf(s);
    float inv = 1.0f / fmaxf(n, 1e-8f);
#pragma unroll
    for (int m = 0; m < 16; m++) {
        buf[m].x *= inv; buf[m].y *= inv; buf[m].z *= inv; buf[m].w *= inv;
        *(float4*)(p + m * 4) = buf[m];
    }
}

// ---------------------------------------------------------------------------
// MFMA banded attention.
// block = (b,h,n,sub): 128 q-rows. wave wid owns rows wid*32..wid*32+31.
// Swapped QK^T: sim_frag = mfma(K_frag, Q_frag) -> C[j][i] (col=i=lane&15).
// hi/lo RN bf16 split, 3 products, for QK, alpha, and V.
// ---------------------------------------------------------------------------
__global__ __launch_bounds__(256, 3) void attn_kernel(
        const float* __restrict__ q, const float* __restrict__ k,
        const float* __restrict__ v, const float* __restrict__ s_v,
        const float* __restrict__ s_r, const float* __restrict__ mask_tab,
        float* __restrict__ out) {
    __shared__ unsigned short Kh[32 * 72];   // [j][d] stride 72
    __shared__ unsigned short Kl[32 * 72];
    __shared__ unsigned short Vh[64 * 40];   // vT: [d][j] stride 40
    __shared__ unsigned short Vl[64 * 40];
    __shared__ unsigned int   aB[4][32 * 33];// per-wave alpha (hi16|lo16), [j][i]
    __shared__ float          msk[256];

    const int bx = blockIdx.x;
    const int h   = bx & 15;          // h in low bits: load balance across CUs
    const int n   = (bx >> 4) & 15;
    const int sub = (bx >> 8) & 1;
    const int b   = bx >> 9;
    const int bh = b * 16 + h;
    const int tid = threadIdx.x;
    const int lane = tid & 63;
    const int wid = tid >> 6;
    const int l15 = lane & 15;
    const int g = lane >> 4;          // 0..3

    msk[tid] = mask_tab[h * 256 + tid];
    const float w = expf(s_v[h]) + 1.0f;
    const float rh = expf(s_r[h]) + 1.0f;

    const int row0 = n * 256 + sub * 128;
    const float* qbase = q + (size_t)bh * 4096 * 64;
    const float* kbase = k + (size_t)bh * 4096 * 64;
    const float* vbase = v + (size_t)bh * 4096 * 64;

    // ---- Q fragments in registers: B-operand, col i = l15 (+if*16+wid*32) ----
    bf16x8 qh[2][2], ql[2][2];        // [if][ks]
#pragma unroll
    for (int f = 0; f < 2; f++) {
#pragma unroll
        for (int ks = 0; ks < 2; ks++) {
            const float* src = qbase + (size_t)(row0 + wid * 32 + f * 16 + l15) * 64
                               + ks * 32 + g * 8;
            f32x4 x0 = *(const f32x4*)src;
            f32x4 x1 = *(const f32x4*)(src + 4);
            float xs[8] = {x0[0], x0[1], x0[2], x0[3], x1[0], x1[1], x1[2], x1[3]};
            unsigned hb[8], lb[8];
#pragma unroll
            for (int e = 0; e < 8; e++) {
                hb[e] = rn_hi(xs[e]);
                lb[e] = rn_hi(xs[e] - __uint_as_float(hb[e]));
            }
            FragU th, tl;
            th.u = make_uint4((hb[0] >> 16) | hb[1], (hb[2] >> 16) | hb[3],
                              (hb[4] >> 16) | hb[5], (hb[6] >> 16) | hb[7]);
            tl.u = make_uint4((lb[0] >> 16) | lb[1], (lb[2] >> 16) | lb[3],
                              (lb[4] >> 16) | lb[5], (lb[6] >> 16) | lb[7]);
            qh[f][ks] = th.f;
            ql[f][ks] = tl.f;
        }
    }

    // ---- j band ----
    int jlo = (int)floorf(256.0f + (float)(sub * 128) - w) + 1;
    if (jlo < 0) jlo = 0;
    if (n == 0 && jlo < 256) jlo = 256;
    jlo &= ~31;
    const int jhi = 256 + sub * 128 + 127;

    // wave-local band for compute guard (i in [iw0, iw0+31])
    const int iw0 = sub * 128 + wid * 32;

    f32x4 acc[2][4];                  // [if][df] PV accumulator
#pragma unroll
    for (int a = 0; a < 2; a++)
#pragma unroll
        for (int d = 0; d < 4; d++) acc[a][d] = (f32x4)(0.0f);

    // staging assignment
    const int kj = tid >> 3;          // 0..31
    const int kd = (tid & 7) * 8;     // 0..56
    const int vj = tid & 31;          // 0..31
    const int vd = (tid >> 5) * 8;    // 0..56

    // preload first tile
    f32x4 kr0, kr1, vr0, vr1;
    {
        const float* ks = kbase + (size_t)((n - 1) * 256 + jlo + kj) * 64 + kd;
        const float* vs = vbase + (size_t)((n - 1) * 256 + jlo + vj) * 64 + vd;
        kr0 = *(const f32x4*)ks;  kr1 = *(const f32x4*)(ks + 4);
        vr0 = *(const f32x4*)vs;  vr1 = *(const f32x4*)(vs + 4);
    }

    for (int jt = jlo; jt <= jhi; jt += 32) {
        __syncthreads();              // previous tile's reads done (also covers msk)
        // split + write K [j][d]
        {
            float xs[8] = {kr0[0], kr0[1], kr0[2], kr0[3], kr1[0], kr1[1], kr1[2], kr1[3]};
            unsigned hb[8], lb[8];
#pragma unroll
            for (int e = 0; e < 8; e++) {
                hb[e] = rn_hi(xs[e]);
                lb[e] = rn_hi(xs[e] - __uint_as_float(hb[e]));
            }
            *(uint4*)&Kh[kj * 72 + kd] =
                make_uint4((hb[0] >> 16) | hb[1], (hb[2] >> 16) | hb[3],
                           (hb[4] >> 16) | hb[5], (hb[6] >> 16) | hb[7]);
            *(uint4*)&Kl[kj * 72 + kd] =
                make_uint4((lb[0] >> 16) | lb[1], (lb[2] >> 16) | lb[3],
                           (lb[4] >> 16) | lb[5], (lb[6] >> 16) | lb[7]);
        }
        // split + write V transposed [d][j]
        {
            float xs[8] = {vr0[0], vr0[1], vr0[2], vr0[3], vr1[0], vr1[1], vr1[2], vr1[3]};
#pragma unroll
            for (int e = 0; e < 8; e++) {
                unsigned hbv = rn_hi(xs[e]);
                unsigned lbv = rn_hi(xs[e] - __uint_as_float(hbv));
                Vh[(vd + e) * 40 + vj] = (unsigned short)(hbv >> 16);
                Vl[(vd + e) * 40 + vj] = (unsigned short)(lbv >> 16);
            }
        }
        // prefetch next tile
        if (jt + 32 <= jhi) {
            const float* ks = kbase + (size_t)((n - 1) * 256 + jt + 32 + kj) * 64 + kd;
            const float* vs = vbase + (size_t)((n - 1) * 256 + jt + 32 + vj) * 64 + vd;
            kr0 = *(const f32x4*)ks;  kr1 = *(const f32x4*)(ks + 4);
            vr0 = *(const f32x4*)vs;  vr1 = *(const f32x4*)(vs + 4);
        }
        __syncthreads();              // tiles visible

        // wave-level live guard
        const bool live = ((float)(jt + 31) > 256.0f + (float)iw0 - w) &&
                          (jt <= 256 + iw0 + 31);
        if (live) {
            // ---- QK^T swapped: sim[jf][if] = K * Q^T ----
            f32x4 sim[2][2];
#pragma unroll
            for (int jf = 0; jf < 2; jf++)
#pragma unroll
                for (int f = 0; f < 2; f++) sim[jf][f] = (f32x4)(0.0f);

#pragma unroll
            for (int jf = 0; jf < 2; jf++) {
#pragma unroll
                for (int ks = 0; ks < 2; ks++) {
                    bf16x8 kah = *(const bf16x8*)&Kh[(jf * 16 + l15) * 72 + ks * 32 + g * 8];
                    bf16x8 kal = *(const bf16x8*)&Kl[(jf * 16 + l15) * 72 + ks * 32 + g * 8];
#pragma unroll
                    for (int f = 0; f < 2; f++) {
                        sim[jf][f] = __builtin_amdgcn_mfma_f32_16x16x32_bf16(
                            kah, qh[f][ks], sim[jf][f], 0, 0, 0);
                        sim[jf][f] = __builtin_amdgcn_mfma_f32_16x16x32_bf16(
                            kah, ql[f][ks], sim[jf][f], 0, 0, 0);
                        sim[jf][f] = __builtin_amdgcn_mfma_f32_16x16x32_bf16(
                            kal, qh[f][ks], sim[jf][f], 0, 0, 0);
                    }
                }
            }

            // ---- alpha + pack into per-wave LDS [j][i] ----
#pragma unroll
            for (int jf = 0; jf < 2; jf++) {
#pragma unroll
                for (int f = 0; f < 2; f++) {
#pragma unroll
                    for (int r = 0; r < 4; r++) {
                        const int jloc = jf * 16 + g * 4 + r;
                        const int iloc = f * 16 + l15;
                        const int rel = (jt + jloc) - 256 - (iw0 + iloc - wid * 32 + iw0 - sub * 128);
                        // NOTE: i_global (within 256-col space) = sub*128 + wid*32 + iloc
                        // rel = jt + jloc - 256 - (sub*128 + wid*32 + iloc)
                        const int relv = (jt + jloc) - 256 - (sub * 128 + wid * 32 + iloc);
                        float m = (relv >= -255 && relv <= 0) ? msk[relv + 255] : 0.0f;
                        float t1 = 1.0f - rh * (1.0f - sim[jf][f][r]);
                        t1 = fmaxf(t1, 0.0f);
                        float alpha = t1 * t1 * m;
                        unsigned ahb = rn_hi(alpha);
                        unsigned alb = rn_hi(alpha - __uint_as_float(ahb));
                        aB[wid][jloc * 33 + iloc] = ahb | (alb >> 16);
                        (void)rel;
                    }
                }
            }

            // ---- PV: repack alpha to A-frags, mfma with vT B-frags ----
#pragma unroll
            for (int f = 0; f < 2; f++) {
                unsigned a8[8];
#pragma unroll
                for (int e = 0; e < 8; e++)
                    a8[e] = aB[wid][(g * 8 + e) * 33 + f * 16 + l15];
                FragU th, tl;
                th.u = make_uint4((a8[0] >> 16) | (a8[1] & 0xFFFF0000u),
                                  (a8[2] >> 16) | (a8[3] & 0xFFFF0000u),
                                  (a8[4] >> 16) | (a8[5] & 0xFFFF0000u),
                                  (a8[6] >> 16) | (a8[7] & 0xFFFF0000u));
                tl.u = make_uint4((a8[0] << 16 >> 16) | (a8[1] << 16),
                                  (a8[2] << 16 >> 16) | (a8[3] << 16),
                                  (a8[4] << 16 >> 16) | (a8[5] << 16),
                                  (a8[6] << 16 >> 16) | (a8[7] << 16));
                // tl words: low16 = elem even lo, high16 = elem odd lo
                bf16x8 aah = th.f, aal = tl.f;
#pragma unroll
                for (int df = 0; df < 4; df++) {
                    bf16x8 vbh = *(const bf16x8*)&Vh[(df * 16 + l15) * 40 + g * 8];
                    bf16x8 vbl = *(const bf16x8*)&Vl[(df * 16 + l15) * 40 + g * 8];
                    acc[f][df] = __builtin_amdgcn_mfma_f32_16x16x32_bf16(
                        aah, vbh, acc[f][df], 0, 0, 0);
                    acc[f][df] = __builtin_amdgcn_mfma_f32_16x16x32_bf16(
                        aah, vbl, acc[f][df], 0, 0, 0);
                    acc[f][df] = __builtin_amdgcn_mfma_f32_16x16x32_bf16(
                        aal, vbh, acc[f][df], 0, 0, 0);
                }
            }
        }
    }

    // ---- epilogue: row tanh-norm + store ----
    // acc[f][df][r]: row i = wid*32 + f*16 + g*4 + r, col d = df*16 + l15
#pragma unroll
    for (int f = 0; f < 2; f++) {
#pragma unroll
        for (int r = 0; r < 4; r++) {
            float p = 0.0f;
#pragma unroll
            for (int df = 0; df < 4; df++) p = fmaf(acc[f][df][r], acc[f][df][r], p);
            p += __shfl_xor(p, 1);
            p += __shfl_xor(p, 2);
            p += __shfl_xor(p, 4);
            p += __shfl_xor(p, 8);
            float nn = sqrtf(p);
            float sc = tanhf(nn) / (nn + 1e-8f);
            const int trow = row0 + wid * 32 + f * 16 + g * 4 + r;
            float* dst = out + ((size_t)(b * 4096 + trow)) * 1024 + h * 64;
#pragma unroll
            for (int df = 0; df < 4; df++)
                dst[df * 16 + l15] = acc[f][df][r] * sc;
        }
    }
}

// ---------------------------------------------------------------------------
extern "C" void kernel_launch(void* const* d_in, const int* in_sizes, int n_in,
                              void* d_out, int out_size, void* d_ws, size_t ws_size,
                              hipStream_t stream) {
    const float* query = (const float*)d_in[0];
    const float* key   = (const float*)d_in[1];
    const float* value = (const float*)d_in[2];
    const float* Wq    = (const float*)d_in[3];
    const float* Wk    = (const float*)d_in[4];
    const float* Wv    = (const float*)d_in[5];
    const float* Wo    = (const float*)d_in[6];
    const float* s_v   = (const float*)d_in[7];
    const float* s_r   = (const float*)d_in[8];
    float* out = (float*)d_out;

    const size_t PROJ = (size_t)2 * 16 * 4096 * 64;
    float* qw = (float*)d_ws;
    float* kw = qw + PROJ;
    float* vw = kw + PROJ;
    float* ao = vw + PROJ;
    float* mask = ao + PROJ;

    mask_tab_kernel<<<dim3(16), dim3(256), 0, stream>>>(s_v, mask);

    dim3 gb(1024 / 128, 8192 / 128);
    gemm_mfma6<1><<<gb, dim3(256), 0, stream>>>(query, Wq, qw, 8192, 1024, 1024);
    gemm_mfma6<1><<<gb, dim3(256), 0, stream>>>(key,   Wk, kw, 8192, 1024, 1024);
    gemm_mfma6<1><<<gb, dim3(256), 0, stream>>>(value, Wv, vw, 8192, 1024, 1024);

    l2norm_kernel<<<dim3(512, 1, 3), dim3(256), 0, stream>>>(qw, kw, vw);

    attn_kernel<<<dim3(1024), dim3(256), 0, stream>>>(qw, kw, vw, s_v, s_r, mask, ao);

    gemm_mfma6<0><<<gb, dim3(256), 0, stream>>>(ao, Wo, out, 8192, 1024, 1024);
}

// Round 4
// 365.978 us; speedup vs baseline: 2.6805x; 1.3849x over previous
//
#include <hip/hip_runtime.h>
#include <math.h>

#ifndef M_PI
#define M_PI 3.14159265358979323846
#endif

typedef short bf16x8 __attribute__((ext_vector_type(8)));
typedef _Float16 f16x8 __attribute__((ext_vector_type(8)));
typedef float f32x4 __attribute__((ext_vector_type(4)));

#define LDS_STRIDE 40   // elems per row (80 B rows): 16B-aligned, bank-friendly

union FragU { uint4 u; bf16x8 f; };
union F16U { uint4 u; f16x8 f; _Float16 h[8]; };

// round-to-nearest-even bf16, returned as bits in HIGH 16 (low 16 zero)
__device__ __forceinline__ unsigned rn_hi(float x) {
    unsigned u = __float_as_uint(x);
    unsigned r = u + 0x7FFFu + ((u >> 16) & 1u);
    return r & 0xFFFF0000u;
}

// ---------------------------------------------------------------------------
// mask table: tab[h][idx], idx = rel + 255, rel in [-255, 0]
// ---------------------------------------------------------------------------
__global__ void mask_tab_kernel(const float* __restrict__ s_v, float* __restrict__ tab) {
    int h = blockIdx.x;
    int idx = threadIdx.x;
    float w = expf(s_v[h]) + 1.0f;
    float rel = (float)(idx - 255);
    float val = 0.0f;
    if (rel > -w) {
        val = 0.5f * (cosf((float)M_PI * rel / w) + 1.0f);
    }
    tab[h * 256 + idx] = val;
}

// ---------------------------------------------------------------------------
// split 8 floats into f16 hi/lo (RN; subtraction exact) and store 16B each.
// ---------------------------------------------------------------------------
__device__ __forceinline__ void split8_f16(_Float16* ph, _Float16* pl, int off,
                                           f32x4 x0, f32x4 x1) {
    float xs[8] = {x0[0], x0[1], x0[2], x0[3], x1[0], x1[1], x1[2], x1[3]};
    F16U H, L;
#pragma unroll
    for (int e = 0; e < 8; e++) {
        _Float16 h = (_Float16)xs[e];
        _Float16 l = (_Float16)(xs[e] - (float)h);
        H.h[e] = h;
        L.h[e] = l;
    }
    *(uint4*)(ph + off) = H.u;
    *(uint4*)(pl + off) = L.u;
}

// ---------------------------------------------------------------------------
// GEMM: C = A * Bm^T via 3-product f16 hi/lo split MFMA.
// A: MxK f32 row-major, Bm: NxK f32 row-major.
// PERM=0: C row-major MxN f32.  PERM=1: C in (B=2,H=16,T=4096,D=64) layout.
// 128x128 tile, BK=32, 256 threads (4 waves, 2x2), 4x4 16x16x32 frags/wave.
// ---------------------------------------------------------------------------
template <int PERM>
__global__ __launch_bounds__(256, 3) void gemm_f16x3(const float* __restrict__ A,
                                                     const float* __restrict__ Bm,
                                                     float* __restrict__ C,
                                                     int M, int N, int K) {
    __shared__ _Float16 Ah[128 * LDS_STRIDE];
    __shared__ _Float16 Al[128 * LDS_STRIDE];
    __shared__ _Float16 Bh[128 * LDS_STRIDE];
    __shared__ _Float16 Bl[128 * LDS_STRIDE];

    const int tid = threadIdx.x;
    const int brow = blockIdx.y * 128;
    const int bcol = blockIdx.x * 128;
    const int lane = tid & 63;
    const int wv = tid >> 6;
    const int wr = wv >> 1;
    const int wc = wv & 1;

    const int srow = tid >> 1;            // 0..127
    const int skb = (tid & 1) * 16;       // 0 / 16
    const float* aptr = A + (size_t)(brow + srow) * K + skb;
    const float* bptr = Bm + (size_t)(bcol + srow) * K + skb;
    const int soff = srow * LDS_STRIDE + skb;

    const int l15 = lane & 15;
    const int k8 = (lane >> 4) * 8;

    f32x4 acc[4][4];
#pragma unroll
    for (int a = 0; a < 4; a++)
#pragma unroll
        for (int b = 0; b < 4; b++) acc[a][b] = (f32x4)(0.0f);

    f32x4 abuf[4], bbuf[4];
#pragma unroll
    for (int m = 0; m < 4; m++) {
        abuf[m] = *(const f32x4*)(aptr + m * 4);
        bbuf[m] = *(const f32x4*)(bptr + m * 4);
    }

#define MFMA_TILE(AF, BF)                                                            \
    do {                                                                             \
        _Pragma("unroll") for (int fr = 0; fr < 4; fr++)                             \
            _Pragma("unroll") for (int fc = 0; fc < 4; fc++)                         \
                acc[fr][fc] = __builtin_amdgcn_mfma_f32_16x16x32_f16(                \
                    AF[fr], BF[fc], acc[fr][fc], 0, 0, 0);                           \
    } while (0)

    for (int kt = 0; kt < K; kt += 32) {
        __syncthreads();   // previous MFMA phase done reading LDS
        split8_f16(Ah, Al, soff,     abuf[0], abuf[1]);
        split8_f16(Ah, Al, soff + 8, abuf[2], abuf[3]);
        split8_f16(Bh, Bl, soff,     bbuf[0], bbuf[1]);
        split8_f16(Bh, Bl, soff + 8, bbuf[2], bbuf[3]);
        if (kt + 32 < K) {   // prefetch next fp32 K-slice; hides under MFMA
#pragma unroll
            for (int m = 0; m < 4; m++) {
                abuf[m] = *(const f32x4*)(aptr + kt + 32 + m * 4);
                bbuf[m] = *(const f32x4*)(bptr + kt + 32 + m * 4);
            }
        }
        __syncthreads();   // LDS tiles visible

        f16x8 ah[4], bh[4], t1[4], t2[4];
#pragma unroll
        for (int f = 0; f < 4; f++) {
            ah[f] = *(const f16x8*)&Ah[(wr * 64 + f * 16 + l15) * LDS_STRIDE + k8];
            bh[f] = *(const f16x8*)&Bh[(wc * 64 + f * 16 + l15) * LDS_STRIDE + k8];
        }
        MFMA_TILE(ah, bh);                      // hi * hi
#pragma unroll
        for (int f = 0; f < 4; f++)
            t1[f] = *(const f16x8*)&Bl[(wc * 64 + f * 16 + l15) * LDS_STRIDE + k8];
        MFMA_TILE(ah, t1);                      // hi * lo
#pragma unroll
        for (int f = 0; f < 4; f++)
            t2[f] = *(const f16x8*)&Al[(wr * 64 + f * 16 + l15) * LDS_STRIDE + k8];
        MFMA_TILE(t2, bh);                      // lo * hi
    }
#undef MFMA_TILE

    // epilogue: C/D layout col = lane&15, row = (lane>>4)*4 + reg
    const int rsub = (lane >> 4) * 4;
#pragma unroll
    for (int fr = 0; fr < 4; fr++) {
#pragma unroll
        for (int fc = 0; fc < 4; fc++) {
            f32x4 v = acc[fr][fc];
            const int i0 = brow + wr * 64 + fr * 16 + rsub;
            const int j = bcol + wc * 64 + fc * 16 + l15;
            if (PERM == 0) {
#pragma unroll
                for (int r = 0; r < 4; r++) C[(size_t)(i0 + r) * N + j] = v[r];
            } else {
                const int h = j >> 6;
                const int d = j & 63;
#pragma unroll
                for (int r = 0; r < 4; r++) {
                    const int i = i0 + r;
                    const int b = i >> 12;
                    const int t = i & 4095;
                    C[(((size_t)(b * 16 + h) * 4096 + t) * 64 + d)] = v[r];
                }
            }
        }
    }
}

// ---------------------------------------------------------------------------
// per-head l2norm over D=64, in place
// ---------------------------------------------------------------------------
__global__ void l2norm_kernel(float* __restrict__ q, float* __restrict__ k,
                              float* __restrict__ v) {
    float* base = (blockIdx.z == 0) ? q : (blockIdx.z == 1) ? k : v;
    size_t row = (size_t)blockIdx.x * blockDim.x + threadIdx.x;
    float* p = base + row * 64;
    float4 buf[16];
    float s = 0.0f;
#pragma unroll
    for (int m = 0; m < 16; m++) {
        buf[m] = *(const float4*)(p + m * 4);
        s = fmaf(buf[m].x, buf[m].x, s);
        s = fmaf(buf[m].y, buf[m].y, s);
        s = fmaf(buf[m].z, buf[m].z, s);
        s = fmaf(buf[m].w, buf[m].w, s);
    }
    float n = sqrtf(s);
    float inv = 1.0f / fmaxf(n, 1e-8f);
#pragma unroll
    for (int m = 0; m < 16; m++) {
        buf[m].x *= inv; buf[m].y *= inv; buf[m].z *= inv; buf[m].w *= inv;
        *(float4*)(p + m * 4) = buf[m];
    }
}

// ---------------------------------------------------------------------------
// MFMA banded attention (unchanged from round 3).
// ---------------------------------------------------------------------------
__global__ __launch_bounds__(256, 3) void attn_kernel(
        const float* __restrict__ q, const float* __restrict__ k,
        const float* __restrict__ v, const float* __restrict__ s_v,
        const float* __restrict__ s_r, const float* __restrict__ mask_tab,
        float* __restrict__ out) {
    __shared__ unsigned short Kh[32 * 72];   // [j][d] stride 72
    __shared__ unsigned short Kl[32 * 72];
    __shared__ unsigned short Vh[64 * 40];   // vT: [d][j] stride 40
    __shared__ unsigned short Vl[64 * 40];
    __shared__ unsigned int   aB[4][32 * 33];// per-wave alpha (hi16|lo16), [j][i]
    __shared__ float          msk[256];

    const int bx = blockIdx.x;
    const int h   = bx & 15;
    const int n   = (bx >> 4) & 15;
    const int sub = (bx >> 8) & 1;
    const int b   = bx >> 9;
    const int bh = b * 16 + h;
    const int tid = threadIdx.x;
    const int lane = tid & 63;
    const int wid = tid >> 6;
    const int l15 = lane & 15;
    const int g = lane >> 4;

    msk[tid] = mask_tab[h * 256 + tid];
    const float w = expf(s_v[h]) + 1.0f;
    const float rh = expf(s_r[h]) + 1.0f;

    const int row0 = n * 256 + sub * 128;
    const float* qbase = q + (size_t)bh * 4096 * 64;
    const float* kbase = k + (size_t)bh * 4096 * 64;
    const float* vbase = v + (size_t)bh * 4096 * 64;

    // ---- Q fragments in registers ----
    bf16x8 qh[2][2], ql[2][2];
#pragma unroll
    for (int f = 0; f < 2; f++) {
#pragma unroll
        for (int ks = 0; ks < 2; ks++) {
            const float* src = qbase + (size_t)(row0 + wid * 32 + f * 16 + l15) * 64
                               + ks * 32 + g * 8;
            f32x4 x0 = *(const f32x4*)src;
            f32x4 x1 = *(const f32x4*)(src + 4);
            float xs[8] = {x0[0], x0[1], x0[2], x0[3], x1[0], x1[1], x1[2], x1[3]};
            unsigned hb[8], lb[8];
#pragma unroll
            for (int e = 0; e < 8; e++) {
                hb[e] = rn_hi(xs[e]);
                lb[e] = rn_hi(xs[e] - __uint_as_float(hb[e]));
            }
            FragU th, tl;
            th.u = make_uint4((hb[0] >> 16) | hb[1], (hb[2] >> 16) | hb[3],
                              (hb[4] >> 16) | hb[5], (hb[6] >> 16) | hb[7]);
            tl.u = make_uint4((lb[0] >> 16) | lb[1], (lb[2] >> 16) | lb[3],
                              (lb[4] >> 16) | lb[5], (lb[6] >> 16) | lb[7]);
            qh[f][ks] = th.f;
            ql[f][ks] = tl.f;
        }
    }

    // ---- j band ----
    int jlo = (int)floorf(256.0f + (float)(sub * 128) - w) + 1;
    if (jlo < 0) jlo = 0;
    if (n == 0 && jlo < 256) jlo = 256;
    jlo &= ~31;
    const int jhi = 256 + sub * 128 + 127;

    const int iw0 = sub * 128 + wid * 32;

    f32x4 acc[2][4];
#pragma unroll
    for (int a = 0; a < 2; a++)
#pragma unroll
        for (int d = 0; d < 4; d++) acc[a][d] = (f32x4)(0.0f);

    const int kj = tid >> 3;
    const int kd = (tid & 7) * 8;
    const int vj = tid & 31;
    const int vd = (tid >> 5) * 8;

    f32x4 kr0, kr1, vr0, vr1;
    {
        const float* ks = kbase + (size_t)((n - 1) * 256 + jlo + kj) * 64 + kd;
        const float* vs = vbase + (size_t)((n - 1) * 256 + jlo + vj) * 64 + vd;
        kr0 = *(const f32x4*)ks;  kr1 = *(const f32x4*)(ks + 4);
        vr0 = *(const f32x4*)vs;  vr1 = *(const f32x4*)(vs + 4);
    }

    for (int jt = jlo; jt <= jhi; jt += 32) {
        __syncthreads();
        {
            float xs[8] = {kr0[0], kr0[1], kr0[2], kr0[3], kr1[0], kr1[1], kr1[2], kr1[3]};
            unsigned hb[8], lb[8];
#pragma unroll
            for (int e = 0; e < 8; e++) {
                hb[e] = rn_hi(xs[e]);
                lb[e] = rn_hi(xs[e] - __uint_as_float(hb[e]));
            }
            *(uint4*)&Kh[kj * 72 + kd] =
                make_uint4((hb[0] >> 16) | hb[1], (hb[2] >> 16) | hb[3],
                           (hb[4] >> 16) | hb[5], (hb[6] >> 16) | hb[7]);
            *(uint4*)&Kl[kj * 72 + kd] =
                make_uint4((lb[0] >> 16) | lb[1], (lb[2] >> 16) | lb[3],
                           (lb[4] >> 16) | lb[5], (lb[6] >> 16) | lb[7]);
        }
        {
            float xs[8] = {vr0[0], vr0[1], vr0[2], vr0[3], vr1[0], vr1[1], vr1[2], vr1[3]};
#pragma unroll
            for (int e = 0; e < 8; e++) {
                unsigned hbv = rn_hi(xs[e]);
                unsigned lbv = rn_hi(xs[e] - __uint_as_float(hbv));
                Vh[(vd + e) * 40 + vj] = (unsigned short)(hbv >> 16);
                Vl[(vd + e) * 40 + vj] = (unsigned short)(lbv >> 16);
            }
        }
        if (jt + 32 <= jhi) {
            const float* ks = kbase + (size_t)((n - 1) * 256 + jt + 32 + kj) * 64 + kd;
            const float* vs = vbase + (size_t)((n - 1) * 256 + jt + 32 + vj) * 64 + vd;
            kr0 = *(const f32x4*)ks;  kr1 = *(const f32x4*)(ks + 4);
            vr0 = *(const f32x4*)vs;  vr1 = *(const f32x4*)(vs + 4);
        }
        __syncthreads();

        const bool live = ((float)(jt + 31) > 256.0f + (float)iw0 - w) &&
                          (jt <= 256 + iw0 + 31);
        if (live) {
            f32x4 sim[2][2];
#pragma unroll
            for (int jf = 0; jf < 2; jf++)
#pragma unroll
                for (int f = 0; f < 2; f++) sim[jf][f] = (f32x4)(0.0f);

#pragma unroll
            for (int jf = 0; jf < 2; jf++) {
#pragma unroll
                for (int ks = 0; ks < 2; ks++) {
                    bf16x8 kah = *(const bf16x8*)&Kh[(jf * 16 + l15) * 72 + ks * 32 + g * 8];
                    bf16x8 kal = *(const bf16x8*)&Kl[(jf * 16 + l15) * 72 + ks * 32 + g * 8];
#pragma unroll
                    for (int f = 0; f < 2; f++) {
                        sim[jf][f] = __builtin_amdgcn_mfma_f32_16x16x32_bf16(
                            kah, qh[f][ks], sim[jf][f], 0, 0, 0);
                        sim[jf][f] = __builtin_amdgcn_mfma_f32_16x16x32_bf16(
                            kah, ql[f][ks], sim[jf][f], 0, 0, 0);
                        sim[jf][f] = __builtin_amdgcn_mfma_f32_16x16x32_bf16(
                            kal, qh[f][ks], sim[jf][f], 0, 0, 0);
                    }
                }
            }

#pragma unroll
            for (int jf = 0; jf < 2; jf++) {
#pragma unroll
                for (int f = 0; f < 2; f++) {
#pragma unroll
                    for (int r = 0; r < 4; r++) {
                        const int jloc = jf * 16 + g * 4 + r;
                        const int iloc = f * 16 + l15;
                        const int relv = (jt + jloc) - 256 - (sub * 128 + wid * 32 + iloc);
                        float m = (relv >= -255 && relv <= 0) ? msk[relv + 255] : 0.0f;
                        float t1 = 1.0f - rh * (1.0f - sim[jf][f][r]);
                        t1 = fmaxf(t1, 0.0f);
                        float alpha = t1 * t1 * m;
                        unsigned ahb = rn_hi(alpha);
                        unsigned alb = rn_hi(alpha - __uint_as_float(ahb));
                        aB[wid][jloc * 33 + iloc] = ahb | (alb >> 16);
                    }
                }
            }

#pragma unroll
            for (int f = 0; f < 2; f++) {
                unsigned a8[8];
#pragma unroll
                for (int e = 0; e < 8; e++)
                    a8[e] = aB[wid][(g * 8 + e) * 33 + f * 16 + l15];
                FragU th, tl;
                th.u = make_uint4((a8[0] >> 16) | (a8[1] & 0xFFFF0000u),
                                  (a8[2] >> 16) | (a8[3] & 0xFFFF0000u),
                                  (a8[4] >> 16) | (a8[5] & 0xFFFF0000u),
                                  (a8[6] >> 16) | (a8[7] & 0xFFFF0000u));
                tl.u = make_uint4((a8[0] << 16 >> 16) | (a8[1] << 16),
                                  (a8[2] << 16 >> 16) | (a8[3] << 16),
                                  (a8[4] << 16 >> 16) | (a8[5] << 16),
                                  (a8[6] << 16 >> 16) | (a8[7] << 16));
                bf16x8 aah = th.f, aal = tl.f;
#pragma unroll
                for (int df = 0; df < 4; df++) {
                    bf16x8 vbh = *(const bf16x8*)&Vh[(df * 16 + l15) * 40 + g * 8];
                    bf16x8 vbl = *(const bf16x8*)&Vl[(df * 16 + l15) * 40 + g * 8];
                    acc[f][df] = __builtin_amdgcn_mfma_f32_16x16x32_bf16(
                        aah, vbh, acc[f][df], 0, 0, 0);
                    acc[f][df] = __builtin_amdgcn_mfma_f32_16x16x32_bf16(
                        aah, vbl, acc[f][df], 0, 0, 0);
                    acc[f][df] = __builtin_amdgcn_mfma_f32_16x16x32_bf16(
                        aal, vbh, acc[f][df], 0, 0, 0);
                }
            }
        }
    }

    // ---- epilogue: row tanh-norm + store ----
#pragma unroll
    for (int f = 0; f < 2; f++) {
#pragma unroll
        for (int r = 0; r < 4; r++) {
            float p = 0.0f;
#pragma unroll
            for (int df = 0; df < 4; df++) p = fmaf(acc[f][df][r], acc[f][df][r], p);
            p += __shfl_xor(p, 1);
            p += __shfl_xor(p, 2);
            p += __shfl_xor(p, 4);
            p += __shfl_xor(p, 8);
            float nn = sqrtf(p);
            float sc = tanhf(nn) / (nn + 1e-8f);
            const int trow = row0 + wid * 32 + f * 16 + g * 4 + r;
            float* dst = out + ((size_t)(b * 4096 + trow)) * 1024 + h * 64;
#pragma unroll
            for (int df = 0; df < 4; df++)
                dst[df * 16 + l15] = acc[f][df][r] * sc;
        }
    }
}

// ---------------------------------------------------------------------------
extern "C" void kernel_launch(void* const* d_in, const int* in_sizes, int n_in,
                              void* d_out, int out_size, void* d_ws, size_t ws_size,
                              hipStream_t stream) {
    const float* query = (const float*)d_in[0];
    const float* key   = (const float*)d_in[1];
    const float* value = (const float*)d_in[2];
    const float* Wq    = (const float*)d_in[3];
    const float* Wk    = (const float*)d_in[4];
    const float* Wv    = (const float*)d_in[5];
    const float* Wo    = (const float*)d_in[6];
    const float* s_v   = (const float*)d_in[7];
    const float* s_r   = (const float*)d_in[8];
    float* out = (float*)d_out;

    const size_t PROJ = (size_t)2 * 16 * 4096 * 64;
    float* qw = (float*)d_ws;
    float* kw = qw + PROJ;
    float* vw = kw + PROJ;
    float* ao = vw + PROJ;
    float* mask = ao + PROJ;

    mask_tab_kernel<<<dim3(16), dim3(256), 0, stream>>>(s_v, mask);

    dim3 gb(1024 / 128, 8192 / 128);
    gemm_f16x3<1><<<gb, dim3(256), 0, stream>>>(query, Wq, qw, 8192, 1024, 1024);
    gemm_f16x3<1><<<gb, dim3(256), 0, stream>>>(key,   Wk, kw, 8192, 1024, 1024);
    gemm_f16x3<1><<<gb, dim3(256), 0, stream>>>(value, Wv, vw, 8192, 1024, 1024);

    l2norm_kernel<<<dim3(512, 1, 3), dim3(256), 0, stream>>>(qw, kw, vw);

    attn_kernel<<<dim3(1024), dim3(256), 0, stream>>>(qw, kw, vw, s_v, s_r, mask, ao);

    gemm_f16x3<0><<<gb, dim3(256), 0, stream>>>(ao, Wo, out, 8192, 1024, 1024);
}

// Round 5
// 338.334 us; speedup vs baseline: 2.8995x; 1.0817x over previous
//
#include <hip/hip_runtime.h>
#include <math.h>

#ifndef M_PI
#define M_PI 3.14159265358979323846
#endif

typedef short bf16x8 __attribute__((ext_vector_type(8)));
typedef _Float16 f16x8 __attribute__((ext_vector_type(8)));
typedef float f32x4 __attribute__((ext_vector_type(4)));

#define LDS_STRIDE 40   // f16 elems per row (80 B rows): 16B-aligned, bank-friendly

union FragU { uint4 u; bf16x8 f; };
union F16U { uint4 u; f16x8 f; _Float16 h[8]; };

// round-to-nearest-even bf16, returned as bits in HIGH 16 (low 16 zero)
__device__ __forceinline__ unsigned rn_hi(float x) {
    unsigned u = __float_as_uint(x);
    unsigned r = u + 0x7FFFu + ((u >> 16) & 1u);
    return r & 0xFFFF0000u;
}

// ---------------------------------------------------------------------------
// mask table: tab[h][idx], idx = rel + 255, rel in [-255, 0]
// ---------------------------------------------------------------------------
__global__ void mask_tab_kernel(const float* __restrict__ s_v, float* __restrict__ tab) {
    int h = blockIdx.x;
    int idx = threadIdx.x;
    float w = expf(s_v[h]) + 1.0f;
    float rel = (float)(idx - 255);
    float val = 0.0f;
    if (rel > -w) {
        val = 0.5f * (cosf((float)M_PI * rel / w) + 1.0f);
    }
    tab[h * 256 + idx] = val;
}

// ---------------------------------------------------------------------------
// split 8 floats into f16 hi/lo (RN; subtraction exact) and store 16B each.
// ---------------------------------------------------------------------------
__device__ __forceinline__ void split8_f16(_Float16* ph, _Float16* pl, int off,
                                           f32x4 x0, f32x4 x1) {
    float xs[8] = {x0[0], x0[1], x0[2], x0[3], x1[0], x1[1], x1[2], x1[3]};
    F16U H, L;
#pragma unroll
    for (int e = 0; e < 8; e++) {
        _Float16 h = (_Float16)xs[e];
        _Float16 l = (_Float16)(xs[e] - (float)h);
        H.h[e] = h;
        L.h[e] = l;
    }
    *(uint4*)(ph + off) = H.u;
    *(uint4*)(pl + off) = L.u;
}

__device__ __forceinline__ void load_ab(const float* aptr, const float* bptr, int kt,
                                        f32x4* ab, f32x4* bb) {
#pragma unroll
    for (int m = 0; m < 4; m++) {
        ab[m] = *(const f32x4*)(aptr + kt + m * 4);
        bb[m] = *(const f32x4*)(bptr + kt + m * 4);
    }
}

__device__ __forceinline__ void stage_ab(_Float16* AhP, _Float16* AlP,
                                         _Float16* BhP, _Float16* BlP, int soff,
                                         const f32x4* ab, const f32x4* bb) {
    split8_f16(AhP, AlP, soff,     ab[0], ab[1]);
    split8_f16(AhP, AlP, soff + 8, ab[2], ab[3]);
    split8_f16(BhP, BlP, soff,     bb[0], bb[1]);
    split8_f16(BhP, BlP, soff + 8, bb[2], bb[3]);
}

// 3-product f16 split MFMA pass over one 128x128x32 LDS tile.
// aoff/boff = (w?*64 + l15)*LDS_STRIDE + k8; frag f at +f*16*LDS_STRIDE.
__device__ __forceinline__ void compute_tile(const _Float16* AhP, const _Float16* AlP,
                                             const _Float16* BhP, const _Float16* BlP,
                                             int aoff, int boff, f32x4 acc[4][4]) {
#define MFMA_TILE(AF, BF)                                                            \
    do {                                                                             \
        _Pragma("unroll") for (int fr = 0; fr < 4; fr++)                             \
            _Pragma("unroll") for (int fc = 0; fc < 4; fc++)                         \
                acc[fr][fc] = __builtin_amdgcn_mfma_f32_16x16x32_f16(                \
                    AF[fr], BF[fc], acc[fr][fc], 0, 0, 0);                           \
    } while (0)
    f16x8 ah[4], bh[4], t1[4], t2[4];
#pragma unroll
    for (int f = 0; f < 4; f++) {
        ah[f] = *(const f16x8*)&AhP[aoff + f * 16 * LDS_STRIDE];
        bh[f] = *(const f16x8*)&BhP[boff + f * 16 * LDS_STRIDE];
    }
    MFMA_TILE(ah, bh);                      // hi * hi
#pragma unroll
    for (int f = 0; f < 4; f++)
        t1[f] = *(const f16x8*)&BlP[boff + f * 16 * LDS_STRIDE];
    MFMA_TILE(ah, t1);                      // hi * lo
#pragma unroll
    for (int f = 0; f < 4; f++)
        t2[f] = *(const f16x8*)&AlP[aoff + f * 16 * LDS_STRIDE];
    MFMA_TILE(t2, bh);                      // lo * hi
#undef MFMA_TILE
}

// ---------------------------------------------------------------------------
// GEMM: C = A * Bm^T via 3-product f16 hi/lo split MFMA.
// Double-buffered LDS (1 barrier/K-step), XCD-chunked block swizzle.
// PERM=0: C row-major MxN f32.  PERM=1: C in (B=2,H=16,T=4096,D=64) layout,
//         with fused per-head l2norm over D=64 (each wave owns one head).
// 128x128 tile, BK=32, 256 threads (4 waves, 2x2), 4x4 16x16x32 frags/wave.
// ---------------------------------------------------------------------------
template <int PERM>
__global__ __launch_bounds__(256, 2) void gemm_f16x3(const float* __restrict__ A,
                                                     const float* __restrict__ Bm,
                                                     float* __restrict__ C,
                                                     int M, int N, int K) {
    __shared__ _Float16 Ah[2][128 * LDS_STRIDE];
    __shared__ _Float16 Al[2][128 * LDS_STRIDE];
    __shared__ _Float16 Bh[2][128 * LDS_STRIDE];
    __shared__ _Float16 Bl[2][128 * LDS_STRIDE];

    const int tid = threadIdx.x;
    // XCD-chunked swizzle: each XCD gets 8 consecutive row-panels x all 8 cols.
    const int bid = blockIdx.x;
    const int swz = (bid & 7) * ((int)gridDim.x >> 3) + (bid >> 3);
    const int brow = (swz >> 3) * 128;
    const int bcol = (swz & 7) * 128;

    const int lane = tid & 63;
    const int wv = tid >> 6;
    const int wr = wv >> 1;
    const int wc = wv & 1;

    const int srow = tid >> 1;            // 0..127
    const int skb = (tid & 1) * 16;       // 0 / 16
    const float* aptr = A + (size_t)(brow + srow) * K + skb;
    const float* bptr = Bm + (size_t)(bcol + srow) * K + skb;
    const int soff = srow * LDS_STRIDE + skb;

    const int l15 = lane & 15;
    const int k8 = (lane >> 4) * 8;
    const int aoff = (wr * 64 + l15) * LDS_STRIDE + k8;
    const int boff = (wc * 64 + l15) * LDS_STRIDE + k8;

    f32x4 acc[4][4];
#pragma unroll
    for (int a = 0; a < 4; a++)
#pragma unroll
        for (int b = 0; b < 4; b++) acc[a][b] = (f32x4)(0.0f);

    const int nt = K >> 5;                // 32 K-steps
    f32x4 a0[4], b0[4], a1[4], b1[4];
    load_ab(aptr, bptr, 0, a0, b0);
    load_ab(aptr, bptr, 32, a1, b1);
    stage_ab(Ah[0], Al[0], Bh[0], Bl[0], soff, a0, b0);
    __syncthreads();

#pragma unroll 1
    for (int t = 0; t < nt; t += 2) {
        // ---- step t (compute buf0, stage buf1 from regs1, prefetch t+2 -> regs0)
        if (t + 2 < nt) load_ab(aptr, bptr, (t + 2) * 32, a0, b0);
        stage_ab(Ah[1], Al[1], Bh[1], Bl[1], soff, a1, b1);
        compute_tile(Ah[0], Al[0], Bh[0], Bl[0], aoff, boff, acc);
        __syncthreads();
        // ---- step t+1 (compute buf1, stage buf0 from regs0, prefetch t+3 -> regs1)
        if (t + 3 < nt) load_ab(aptr, bptr, (t + 3) * 32, a1, b1);
        if (t + 2 < nt) stage_ab(Ah[0], Al[0], Bh[0], Bl[0], soff, a0, b0);
        compute_tile(Ah[1], Al[1], Bh[1], Bl[1], aoff, boff, acc);
        __syncthreads();
    }

    // ---- fused l2norm (PERM=1 only): each wave owns one head's 64 cols.
    if (PERM == 1) {
#pragma unroll
        for (int fr = 0; fr < 4; fr++) {
#pragma unroll
            for (int r = 0; r < 4; r++) {
                float p = 0.0f;
#pragma unroll
                for (int fc = 0; fc < 4; fc++)
                    p = fmaf(acc[fr][fc][r], acc[fr][fc][r], p);
                p += __shfl_xor(p, 1);
                p += __shfl_xor(p, 2);
                p += __shfl_xor(p, 4);
                p += __shfl_xor(p, 8);
                float inv = 1.0f / fmaxf(sqrtf(p), 1e-8f);
#pragma unroll
                for (int fc = 0; fc < 4; fc++) acc[fr][fc][r] *= inv;
            }
        }
    }

    // epilogue: C/D layout col = lane&15, row = (lane>>4)*4 + reg
    const int rsub = (lane >> 4) * 4;
#pragma unroll
    for (int fr = 0; fr < 4; fr++) {
#pragma unroll
        for (int fc = 0; fc < 4; fc++) {
            f32x4 v = acc[fr][fc];
            const int i0 = brow + wr * 64 + fr * 16 + rsub;
            const int j = bcol + wc * 64 + fc * 16 + l15;
            if (PERM == 0) {
#pragma unroll
                for (int r = 0; r < 4; r++) C[(size_t)(i0 + r) * N + j] = v[r];
            } else {
                const int h = j >> 6;
                const int d = j & 63;
#pragma unroll
                for (int r = 0; r < 4; r++) {
                    const int i = i0 + r;
                    const int b = i >> 12;
                    const int t = i & 4095;
                    C[(((size_t)(b * 16 + h) * 4096 + t) * 64 + d)] = v[r];
                }
            }
        }
    }
}

// ---------------------------------------------------------------------------
// MFMA banded attention (unchanged from round 3/4).
// ---------------------------------------------------------------------------
__global__ __launch_bounds__(256, 3) void attn_kernel(
        const float* __restrict__ q, const float* __restrict__ k,
        const float* __restrict__ v, const float* __restrict__ s_v,
        const float* __restrict__ s_r, const float* __restrict__ mask_tab,
        float* __restrict__ out) {
    __shared__ unsigned short Kh[32 * 72];   // [j][d] stride 72
    __shared__ unsigned short Kl[32 * 72];
    __shared__ unsigned short Vh[64 * 40];   // vT: [d][j] stride 40
    __shared__ unsigned short Vl[64 * 40];
    __shared__ unsigned int   aB[4][32 * 33];// per-wave alpha (hi16|lo16), [j][i]
    __shared__ float          msk[256];

    const int bx = blockIdx.x;
    const int h   = bx & 15;
    const int n   = (bx >> 4) & 15;
    const int sub = (bx >> 8) & 1;
    const int b   = bx >> 9;
    const int bh = b * 16 + h;
    const int tid = threadIdx.x;
    const int lane = tid & 63;
    const int wid = tid >> 6;
    const int l15 = lane & 15;
    const int g = lane >> 4;

    msk[tid] = mask_tab[h * 256 + tid];
    const float w = expf(s_v[h]) + 1.0f;
    const float rh = expf(s_r[h]) + 1.0f;

    const int row0 = n * 256 + sub * 128;
    const float* qbase = q + (size_t)bh * 4096 * 64;
    const float* kbase = k + (size_t)bh * 4096 * 64;
    const float* vbase = v + (size_t)bh * 4096 * 64;

    // ---- Q fragments in registers ----
    bf16x8 qh[2][2], ql[2][2];
#pragma unroll
    for (int f = 0; f < 2; f++) {
#pragma unroll
        for (int ks = 0; ks < 2; ks++) {
            const float* src = qbase + (size_t)(row0 + wid * 32 + f * 16 + l15) * 64
                               + ks * 32 + g * 8;
            f32x4 x0 = *(const f32x4*)src;
            f32x4 x1 = *(const f32x4*)(src + 4);
            float xs[8] = {x0[0], x0[1], x0[2], x0[3], x1[0], x1[1], x1[2], x1[3]};
            unsigned hb[8], lb[8];
#pragma unroll
            for (int e = 0; e < 8; e++) {
                hb[e] = rn_hi(xs[e]);
                lb[e] = rn_hi(xs[e] - __uint_as_float(hb[e]));
            }
            FragU th, tl;
            th.u = make_uint4((hb[0] >> 16) | hb[1], (hb[2] >> 16) | hb[3],
                              (hb[4] >> 16) | hb[5], (hb[6] >> 16) | hb[7]);
            tl.u = make_uint4((lb[0] >> 16) | lb[1], (lb[2] >> 16) | lb[3],
                              (lb[4] >> 16) | lb[5], (lb[6] >> 16) | lb[7]);
            qh[f][ks] = th.f;
            ql[f][ks] = tl.f;
        }
    }

    // ---- j band ----
    int jlo = (int)floorf(256.0f + (float)(sub * 128) - w) + 1;
    if (jlo < 0) jlo = 0;
    if (n == 0 && jlo < 256) jlo = 256;
    jlo &= ~31;
    const int jhi = 256 + sub * 128 + 127;

    const int iw0 = sub * 128 + wid * 32;

    f32x4 acc[2][4];
#pragma unroll
    for (int a = 0; a < 2; a++)
#pragma unroll
        for (int d = 0; d < 4; d++) acc[a][d] = (f32x4)(0.0f);

    const int kj = tid >> 3;
    const int kd = (tid & 7) * 8;
    const int vj = tid & 31;
    const int vd = (tid >> 5) * 8;

    f32x4 kr0, kr1, vr0, vr1;
    {
        const float* ks = kbase + (size_t)((n - 1) * 256 + jlo + kj) * 64 + kd;
        const float* vs = vbase + (size_t)((n - 1) * 256 + jlo + vj) * 64 + vd;
        kr0 = *(const f32x4*)ks;  kr1 = *(const f32x4*)(ks + 4);
        vr0 = *(const f32x4*)vs;  vr1 = *(const f32x4*)(vs + 4);
    }

    for (int jt = jlo; jt <= jhi; jt += 32) {
        __syncthreads();
        {
            float xs[8] = {kr0[0], kr0[1], kr0[2], kr0[3], kr1[0], kr1[1], kr1[2], kr1[3]};
            unsigned hb[8], lb[8];
#pragma unroll
            for (int e = 0; e < 8; e++) {
                hb[e] = rn_hi(xs[e]);
                lb[e] = rn_hi(xs[e] - __uint_as_float(hb[e]));
            }
            *(uint4*)&Kh[kj * 72 + kd] =
                make_uint4((hb[0] >> 16) | hb[1], (hb[2] >> 16) | hb[3],
                           (hb[4] >> 16) | hb[5], (hb[6] >> 16) | hb[7]);
            *(uint4*)&Kl[kj * 72 + kd] =
                make_uint4((lb[0] >> 16) | lb[1], (lb[2] >> 16) | lb[3],
                           (lb[4] >> 16) | lb[5], (lb[6] >> 16) | lb[7]);
        }
        {
            float xs[8] = {vr0[0], vr0[1], vr0[2], vr0[3], vr1[0], vr1[1], vr1[2], vr1[3]};
#pragma unroll
            for (int e = 0; e < 8; e++) {
                unsigned hbv = rn_hi(xs[e]);
                unsigned lbv = rn_hi(xs[e] - __uint_as_float(hbv));
                Vh[(vd + e) * 40 + vj] = (unsigned short)(hbv >> 16);
                Vl[(vd + e) * 40 + vj] = (unsigned short)(lbv >> 16);
            }
        }
        if (jt + 32 <= jhi) {
            const float* ks = kbase + (size_t)((n - 1) * 256 + jt + 32 + kj) * 64 + kd;
            const float* vs = vbase + (size_t)((n - 1) * 256 + jt + 32 + vj) * 64 + vd;
            kr0 = *(const f32x4*)ks;  kr1 = *(const f32x4*)(ks + 4);
            vr0 = *(const f32x4*)vs;  vr1 = *(const f32x4*)(vs + 4);
        }
        __syncthreads();

        const bool live = ((float)(jt + 31) > 256.0f + (float)iw0 - w) &&
                          (jt <= 256 + iw0 + 31);
        if (live) {
            f32x4 sim[2][2];
#pragma unroll
            for (int jf = 0; jf < 2; jf++)
#pragma unroll
                for (int f = 0; f < 2; f++) sim[jf][f] = (f32x4)(0.0f);

#pragma unroll
            for (int jf = 0; jf < 2; jf++) {
#pragma unroll
                for (int ks = 0; ks < 2; ks++) {
                    bf16x8 kah = *(const bf16x8*)&Kh[(jf * 16 + l15) * 72 + ks * 32 + g * 8];
                    bf16x8 kal = *(const bf16x8*)&Kl[(jf * 16 + l15) * 72 + ks * 32 + g * 8];
#pragma unroll
                    for (int f = 0; f < 2; f++) {
                        sim[jf][f] = __builtin_amdgcn_mfma_f32_16x16x32_bf16(
                            kah, qh[f][ks], sim[jf][f], 0, 0, 0);
                        sim[jf][f] = __builtin_amdgcn_mfma_f32_16x16x32_bf16(
                            kah, ql[f][ks], sim[jf][f], 0, 0, 0);
                        sim[jf][f] = __builtin_amdgcn_mfma_f32_16x16x32_bf16(
                            kal, qh[f][ks], sim[jf][f], 0, 0, 0);
                    }
                }
            }

#pragma unroll
            for (int jf = 0; jf < 2; jf++) {
#pragma unroll
                for (int f = 0; f < 2; f++) {
#pragma unroll
                    for (int r = 0; r < 4; r++) {
                        const int jloc = jf * 16 + g * 4 + r;
                        const int iloc = f * 16 + l15;
                        const int relv = (jt + jloc) - 256 - (sub * 128 + wid * 32 + iloc);
                        float m = (relv >= -255 && relv <= 0) ? msk[relv + 255] : 0.0f;
                        float t1 = 1.0f - rh * (1.0f - sim[jf][f][r]);
                        t1 = fmaxf(t1, 0.0f);
                        float alpha = t1 * t1 * m;
                        unsigned ahb = rn_hi(alpha);
                        unsigned alb = rn_hi(alpha - __uint_as_float(ahb));
                        aB[wid][jloc * 33 + iloc] = ahb | (alb >> 16);
                    }
                }
            }

#pragma unroll
            for (int f = 0; f < 2; f++) {
                unsigned a8[8];
#pragma unroll
                for (int e = 0; e < 8; e++)
                    a8[e] = aB[wid][(g * 8 + e) * 33 + f * 16 + l15];
                FragU th, tl;
                th.u = make_uint4((a8[0] >> 16) | (a8[1] & 0xFFFF0000u),
                                  (a8[2] >> 16) | (a8[3] & 0xFFFF0000u),
                                  (a8[4] >> 16) | (a8[5] & 0xFFFF0000u),
                                  (a8[6] >> 16) | (a8[7] & 0xFFFF0000u));
                tl.u = make_uint4((a8[0] << 16 >> 16) | (a8[1] << 16),
                                  (a8[2] << 16 >> 16) | (a8[3] << 16),
                                  (a8[4] << 16 >> 16) | (a8[5] << 16),
                                  (a8[6] << 16 >> 16) | (a8[7] << 16));
                bf16x8 aah = th.f, aal = tl.f;
#pragma unroll
                for (int df = 0; df < 4; df++) {
                    bf16x8 vbh = *(const bf16x8*)&Vh[(df * 16 + l15) * 40 + g * 8];
                    bf16x8 vbl = *(const bf16x8*)&Vl[(df * 16 + l15) * 40 + g * 8];
                    acc[f][df] = __builtin_amdgcn_mfma_f32_16x16x32_bf16(
                        aah, vbh, acc[f][df], 0, 0, 0);
                    acc[f][df] = __builtin_amdgcn_mfma_f32_16x16x32_bf16(
                        aah, vbl, acc[f][df], 0, 0, 0);
                    acc[f][df] = __builtin_amdgcn_mfma_f32_16x16x32_bf16(
                        aal, vbh, acc[f][df], 0, 0, 0);
                }
            }
        }
    }

    // ---- epilogue: row tanh-norm + store ----
#pragma unroll
    for (int f = 0; f < 2; f++) {
#pragma unroll
        for (int r = 0; r < 4; r++) {
            float p = 0.0f;
#pragma unroll
            for (int df = 0; df < 4; df++) p = fmaf(acc[f][df][r], acc[f][df][r], p);
            p += __shfl_xor(p, 1);
            p += __shfl_xor(p, 2);
            p += __shfl_xor(p, 4);
            p += __shfl_xor(p, 8);
            float nn = sqrtf(p);
            float sc = tanhf(nn) / (nn + 1e-8f);
            const int trow = row0 + wid * 32 + f * 16 + g * 4 + r;
            float* dst = out + ((size_t)(b * 4096 + trow)) * 1024 + h * 64;
#pragma unroll
            for (int df = 0; df < 4; df++)
                dst[df * 16 + l15] = acc[f][df][r] * sc;
        }
    }
}

// ---------------------------------------------------------------------------
extern "C" void kernel_launch(void* const* d_in, const int* in_sizes, int n_in,
                              void* d_out, int out_size, void* d_ws, size_t ws_size,
                              hipStream_t stream) {
    const float* query = (const float*)d_in[0];
    const float* key   = (const float*)d_in[1];
    const float* value = (const float*)d_in[2];
    const float* Wq    = (const float*)d_in[3];
    const float* Wk    = (const float*)d_in[4];
    const float* Wv    = (const float*)d_in[5];
    const float* Wo    = (const float*)d_in[6];
    const float* s_v   = (const float*)d_in[7];
    const float* s_r   = (const float*)d_in[8];
    float* out = (float*)d_out;

    const size_t PROJ = (size_t)2 * 16 * 4096 * 64;
    float* qw = (float*)d_ws;
    float* kw = qw + PROJ;
    float* vw = kw + PROJ;
    float* ao = vw + PROJ;
    float* mask = ao + PROJ;

    mask_tab_kernel<<<dim3(16), dim3(256), 0, stream>>>(s_v, mask);

    // 1-D grid (8 col-blocks x 64 row-blocks), XCD-chunk-swizzled in-kernel.
    gemm_f16x3<1><<<dim3(512), dim3(256), 0, stream>>>(query, Wq, qw, 8192, 1024, 1024);
    gemm_f16x3<1><<<dim3(512), dim3(256), 0, stream>>>(key,   Wk, kw, 8192, 1024, 1024);
    gemm_f16x3<1><<<dim3(512), dim3(256), 0, stream>>>(value, Wv, vw, 8192, 1024, 1024);

    attn_kernel<<<dim3(1024), dim3(256), 0, stream>>>(qw, kw, vw, s_v, s_r, mask, ao);

    gemm_f16x3<0><<<dim3(512), dim3(256), 0, stream>>>(ao, Wo, out, 8192, 1024, 1024);
}